// Round 7
// baseline (556.961 us; speedup 1.0000x reference)
//
#include <hip/hip_runtime.h>
#include <math.h>
#include <stdint.h>

#define B_    32
#define E_    256
#define F_    256
#define H_    512
#define V_    32000
#define G4    2048

typedef unsigned short u16;
typedef unsigned long long u64;
typedef __attribute__((ext_vector_type(8))) short bf16x8;
typedef __attribute__((ext_vector_type(4))) float f32x4;

__device__ __forceinline__ float fsig(float x) {   // 1/(1+e^-x), v_exp+v_rcp
  return __builtin_amdgcn_rcpf(1.f + __expf(-x));
}
__device__ __forceinline__ float ftanh(float x) {  // 1 - 2/(e^2x+1)
  return 1.f - 2.f * __builtin_amdgcn_rcpf(1.f + __expf(2.f * x));
}

__device__ __forceinline__ u16 f2bf(float f) {
  uint32_t u = __float_as_uint(f);
  uint32_t r = (u + 0x7FFFu + ((u >> 16) & 1u)) >> 16;   // RNE
  return (u16)r;
}
__device__ __forceinline__ uint32_t pack2(float a, float b) {
  return (uint32_t)f2bf(a) | ((uint32_t)f2bf(b) << 16);
}

#define GLOAD16(gp, lp) __builtin_amdgcn_global_load_lds( \
    (const __attribute__((address_space(1))) uint32_t*)(const void*)(gp), \
    (__attribute__((address_space(3))) uint32_t*)(void*)(lp), 16, 0, 0)

#define ALOAD(P) __hip_atomic_load((P), __ATOMIC_RELAXED, __HIP_MEMORY_SCOPE_AGENT)
#define ASTORE(P, V) __hip_atomic_store((P), (V), __ATOMIC_RELAXED, __HIP_MEMORY_SCOPE_AGENT)

// ---------------- fused init ---------------------------------------------------------
// flags layout: [64 t][64 consumer_block][128 producer] u32 (512B per (t,cb))
__global__ void init_all(float* pooled, uint32_t* flg1, uint32_t* flg2,
                         u16* h1d, u16* h2a,
                         const float* bi1, const float* bh1,
                         const float* bi2, const float* bh2,
                         float* bs1, float* bs2, float* out) {
  int i = blockIdx.x * blockDim.x + threadIdx.x, st = gridDim.x * blockDim.x;
  for (int k = i; k < 24576; k += st) pooled[k] = 0.f;
  for (int k = i; k < 524288; k += st) {
    uint32_t v = (k < 8192) ? 1u : 0u;            // t=0 ready for all consumers
    flg1[k] = v; flg2[k] = v;
  }
  uint4 z = {0u, 0u, 0u, 0u};
  for (int k = i; k < 2048; k += st) { ((uint4*)h1d)[k] = z; ((uint4*)h2a)[k] = z; }
  for (int k = i; k < G4; k += st) { bs1[k] = bi1[k] + bh1[k]; bs2[k] = bi2[k] + bh2[k]; }
  for (int k = i; k < B_ * V_; k += st) {
    int b = k / V_, v = k - b * V_;
    out[(size_t)b * 64 * V_ + v] = 0.f;
  }
}

// ---------------- fused bf16 conversion of 5 weight tensors --------------------------
__global__ void cvt_all(const float* s0, u16* d0, const float* s1, u16* d1,
                        const float* s2, u16* d2, const float* s3, u16* d3,
                        const float* s4, u16* d4) {
  int i = blockIdx.x * blockDim.x + threadIdx.x, st = gridDim.x * blockDim.x;
  for (; i < 2637824; i += st) {
    int j = i; const float* s; u16* d;
    if (j < 2048000) { s = s0; d = d0; }
    else if ((j -= 2048000) < 196608) { s = s1; d = d1; }
    else if ((j -= 196608) < 131072) { s = s2; d = d2; }
    else if ((j -= 131072) < 131072) { s = s3; d = d3; }
    else { j -= 131072; s = s4; d = d4; }
    const float4* sp = (const float4*)s + 2 * (size_t)j;
    float4 a = sp[0], b = sp[1];
    uint4 u;
    u.x = pack2(a.x, a.y); u.y = pack2(a.z, a.w);
    u.z = pack2(b.x, b.y); u.w = pack2(b.z, b.w);
    *((uint4*)d + j) = u;
  }
}

// conv weights (F,E,kw) -> bf16 [f][j*256+e], all 3 in one kernel
__global__ void wtj_all(const float* w3, u16* t3, const float* w4, u16* t4,
                        const float* w5, u16* t5) {
  int i = blockIdx.x * blockDim.x + threadIdx.x, st = gridDim.x * blockDim.x;
  for (; i < 786432; i += st) {
    int j = i; const float* w; u16* wt; int kw;
    if (j < 196608) { w = w3; wt = t3; kw = 3; }
    else if ((j -= 196608) < 262144) { w = w4; wt = t4; kw = 4; }
    else { j -= 262144; w = w5; wt = t5; kw = 5; }
    int f = j / (kw * 256);
    int r = j - f * (kw * 256);
    int jj = r >> 8, e = r & 255;
    wt[j] = f2bf(w[(f * 256 + e) * kw + jj]);
  }
}

// X1 rows (bf16): [dec_emb(tok) | enc_out], rows r=t*32+b, pad rows zeroed
__global__ void build_x1(const int* __restrict__ trg, const float* __restrict__ demb,
                         const float* __restrict__ enco, u16* __restrict__ X1) {
  int r = blockIdx.x, tid = threadIdx.x;
  u16* row = X1 + (size_t)r * 768;
  if (r >= 2016) { row[tid] = 0; row[256 + tid] = 0; row[512 + tid] = 0; return; }
  int t = r >> 5, b = r & 31;
  int tok = trg[b * 64 + t];
  row[tid]       = f2bf(demb[(size_t)tok * E_ + tid]);
  row[256 + tid] = f2bf(enco[b * H_ + tid]);
  row[512 + tid] = f2bf(enco[b * H_ + 256 + tid]);
}

// ---------------- small fp32 GEMM (fc1/fc2) ----------------
__global__ void gemm_small(const float* __restrict__ A, const float* __restrict__ W,
                           const float* __restrict__ bias, float* __restrict__ C,
                           int K, int N, int relu) {
  int nl = threadIdx.x & 7, b = threadIdx.x >> 3;
  int n = blockIdx.x * 8 + nl;
  const float* a = A + b * K;
  const float* w = W + (size_t)n * K;
  float acc = 0.f;
  for (int k = 0; k < K; k += 4) {
    float4 av = *reinterpret_cast<const float4*>(&a[k]);
    float4 wv = *reinterpret_cast<const float4*>(&w[k]);
    acc = fmaf(av.x, wv.x, acc); acc = fmaf(av.y, wv.y, acc);
    acc = fmaf(av.z, wv.z, acc); acc = fmaf(av.w, wv.w, acc);
  }
  acc += bias[n];
  if (relu) acc = fmaxf(acc, 0.f);
  C[b * N + n] = acc;
}

// ---------------- bf16 MFMA GEMM, 128x128 tile, BK=32, double-buffered --------------
// RM=0: C[m*N+col]=acc+bias   RM=1: scatter row r=t*32+b -> out[b][t+1][:]
template<int RM>
__global__ __launch_bounds__(256)
void gemm_mfma(const u16* __restrict__ A, const u16* __restrict__ Bw,
               const float* __restrict__ bias, float* __restrict__ C,
               int M, int N, int K) {
  __shared__ char smem[32768];
  const int tid = threadIdx.x;
  const int wid = tid >> 6, lane = tid & 63;
  const int hi = lane >> 4, lo = lane & 15;
  const int wr = wid >> 1, wc = wid & 1;
  const int m0 = blockIdx.x * 128, n0 = blockIdx.y * 128;
  const int NT = K >> 5;
  const int srow = lane >> 2, sc = lane & 3;

  f32x4 acc[4][4];
#pragma unroll
  for (int i = 0; i < 4; ++i)
#pragma unroll
    for (int j = 0; j < 4; ++j) acc[i][j] = (f32x4){0.f, 0.f, 0.f, 0.f};

  for (int t = -1; t < NT; ++t) {
    int ts = t + 1;
    if (ts < NT) {
      char* base = smem + (ts & 1) * 16384;
      int k0 = ts << 5;
#pragma unroll
      for (int q = 0; q < 2; ++q) {
        int row = (wid + q * 4) * 16 + srow;
        int gc = sc ^ (row & 3);
        const char* gp = (const char*)A + (((size_t)(m0 + row) * K + k0) << 1) + gc * 16;
        GLOAD16(gp, base + (wid + q * 4) * 1024);
      }
#pragma unroll
      for (int q = 0; q < 2; ++q) {
        int row = (wid + q * 4) * 16 + srow;
        int gc = sc ^ (row & 3);
        const char* gp = (const char*)Bw + (((size_t)(n0 + row) * K + k0) << 1) + gc * 16;
        GLOAD16(gp, base + 8192 + (wid + q * 4) * 1024);
      }
    }
    if (t >= 0) {
      char* base = smem + (t & 1) * 16384;
      bf16x8 af[4], bfr[4];
#pragma unroll
      for (int mi = 0; mi < 4; ++mi) {
        int row = wr * 64 + mi * 16 + lo;
        af[mi] = *(const bf16x8*)(base + row * 64 + ((hi ^ (row & 3)) << 4));
      }
#pragma unroll
      for (int ni = 0; ni < 4; ++ni) {
        int row = wc * 64 + ni * 16 + lo;
        bfr[ni] = *(const bf16x8*)(base + 8192 + row * 64 + ((hi ^ (row & 3)) << 4));
      }
#pragma unroll
      for (int mi = 0; mi < 4; ++mi)
#pragma unroll
        for (int ni = 0; ni < 4; ++ni)
          acc[mi][ni] = __builtin_amdgcn_mfma_f32_16x16x32_bf16(af[mi], bfr[ni], acc[mi][ni], 0, 0, 0);
    }
    __syncthreads();
  }

#pragma unroll
  for (int mi = 0; mi < 4; ++mi)
#pragma unroll
    for (int r = 0; r < 4; ++r) {
      int m = m0 + wr * 64 + mi * 16 + hi * 4 + r;
      if (m >= M) continue;
      size_t rowbase;
      if (RM == 1) { int t2 = m >> 5, b = m & 31; rowbase = ((size_t)b * 64 + t2 + 1) * (size_t)V_; }
      else rowbase = (size_t)m * N;
#pragma unroll
      for (int ni = 0; ni < 4; ++ni) {
        int col = n0 + wc * 64 + ni * 16 + lo;
        C[rowbase + col] = acc[mi][ni][r] + bias[col];
      }
    }
}

// ---------------- conv via implicit im2col + fused relu/maxpool, z = filter set ------
__global__ __launch_bounds__(256)
void conv_mfma(const u16* __restrict__ wt3, const u16* __restrict__ wt4,
               const u16* __restrict__ wt5,
               const float* __restrict__ cb3, const float* __restrict__ cb4,
               const float* __restrict__ cb5,
               float* __restrict__ pooled,
               const int* __restrict__ srcTok, const float* __restrict__ emb) {
  const int z = blockIdx.z;
  const u16* Bw = (z == 0) ? wt3 : (z == 1) ? wt4 : wt5;
  const float* bias = (z == 0) ? cb3 : (z == 1) ? cb4 : cb5;
  const int K = 768 + 256 * z, kw = 3 + z, poolOff = 256 * z;

  __shared__ char smem[32768];
  const int tid = threadIdx.x;
  const int wid = tid >> 6, lane = tid & 63;
  const int hi = lane >> 4, lo = lane & 15;
  const int wr = wid >> 1, wc = wid & 1;
  const int m0 = blockIdx.x * 128, n0 = blockIdx.y * 128;
  const int NT = K >> 5;
  const int srow = lane >> 2, sc = lane & 3;

  f32x4 acc[4][4];
#pragma unroll
  for (int i = 0; i < 4; ++i)
#pragma unroll
    for (int j = 0; j < 4; ++j) acc[i][j] = (f32x4){0.f, 0.f, 0.f, 0.f};

  for (int t = -1; t < NT; ++t) {
    int ts = t + 1;
    if (ts < NT) {
      char* base = smem + (ts & 1) * 16384;
      int k0 = ts << 5;
      {  // A: gather from embeddings (im2col in LDS)
        int j = k0 >> 8, e0 = k0 & 255;
        int row = tid >> 1;
        int m = m0 + row;
        int s = m & 511, b = m >> 9;
        int sj = s + j;
        int tok = (sj < 512) ? srcTok[b * 512 + sj] : -1;
#pragma unroll
        for (int q = 0; q < 2; ++q) {
          int cg = (tid & 1) * 2 + q;
          uint4 u;
          if (tok >= 0) {
            const float* ep = emb + (size_t)tok * 256 + e0 + cg * 8;
            float4 f0 = *(const float4*)(ep);
            float4 f1 = *(const float4*)(ep + 4);
            u.x = pack2(f0.x, f0.y); u.y = pack2(f0.z, f0.w);
            u.z = pack2(f1.x, f1.y); u.w = pack2(f1.z, f1.w);
          } else u = (uint4){0, 0, 0, 0};
          int c = cg ^ (row & 3);
          *(uint4*)(base + row * 64 + c * 16) = u;
        }
      }
#pragma unroll
      for (int q = 0; q < 2; ++q) {
        int row = (wid + q * 4) * 16 + srow;
        int gc = sc ^ (row & 3);
        const char* gp = (const char*)Bw + (((size_t)(n0 + row) * K + k0) << 1) + gc * 16;
        GLOAD16(gp, base + 8192 + (wid + q * 4) * 1024);
      }
    }
    if (t >= 0) {
      char* base = smem + (t & 1) * 16384;
      bf16x8 af[4], bfr[4];
#pragma unroll
      for (int mi = 0; mi < 4; ++mi) {
        int row = wr * 64 + mi * 16 + lo;
        af[mi] = *(const bf16x8*)(base + row * 64 + ((hi ^ (row & 3)) << 4));
      }
#pragma unroll
      for (int ni = 0; ni < 4; ++ni) {
        int row = wc * 64 + ni * 16 + lo;
        bfr[ni] = *(const bf16x8*)(base + 8192 + row * 64 + ((hi ^ (row & 3)) << 4));
      }
#pragma unroll
      for (int mi = 0; mi < 4; ++mi)
#pragma unroll
        for (int ni = 0; ni < 4; ++ni)
          acc[mi][ni] = __builtin_amdgcn_mfma_f32_16x16x32_bf16(af[mi], bfr[ni], acc[mi][ni], 0, 0, 0);
    }
    __syncthreads();
  }

  int b = m0 >> 9;
  int slim = 512 - kw;
#pragma unroll
  for (int ni = 0; ni < 4; ++ni) {
    int col = n0 + wc * 64 + ni * 16 + lo;
    float bv = bias[col];
    float mx = 0.f;
#pragma unroll
    for (int mi = 0; mi < 4; ++mi)
#pragma unroll
      for (int r = 0; r < 4; ++r) {
        int m = m0 + wr * 64 + mi * 16 + hi * 4 + r;
        int s = m & 511;
        float v = acc[mi][ni][r] + bv;
        if (s <= slim && v > mx) mx = v;
      }
    atomicMax((int*)&pooled[b * 768 + poolOff + col], __float_as_int(mx));
  }
}

// ---------------- fused 2-layer persistent LSTM, private flag mailboxes --------------
// Data: plain bf16 agent-scope stores. Flags: flg[t][consumer_block][producer] —
// producer wave drains vmcnt then fans out its flag to 64 private mailboxes (1 store
// per lane). Consumer waves poll their OWN 512B mailbox row with coalesced loads:
// no flag line is shared across blocks => no LLC same-line poll congestion.
__global__ __launch_bounds__(256, 1)
void lstm_fused(const float* __restrict__ pre,
                const u16* __restrict__ whh1,
                const u16* __restrict__ wih2, const u16* __restrict__ whh2,
                const float* __restrict__ bs2,
                uint32_t* __restrict__ flg1, uint32_t* __restrict__ flg2,
                u16* __restrict__ h1d, u16* __restrict__ h2a) {
  __shared__ char smem[74752];
  const int tid = threadIdx.x;
  const int wid = tid >> 6, lane = tid & 63, hi = lane >> 4, lo = lane & 15;
  const int hrow = tid >> 3, k8 = tid & 7;
  const int pb = hrow, pj0 = k8 * 2;
  const int cb = blockIdx.x;                       // consumer mailbox row

#define WAVE_DRAIN() asm volatile("s_waitcnt vmcnt(0)" ::: "memory")
#define POLL1(P) while (ALOAD(P) == 0u) __builtin_amdgcn_s_sleep(1);
#define POLL2(P, Q) for (;;) { uint32_t x_ = ALOAD(P), y_ = ALOAD(Q); \
                               if (x_ & y_) break; __builtin_amdgcn_s_sleep(1); }
// flag fan-out: every lane stores producer pid's flag into consumer 'lane''s mailbox
#define PUBF(ARR, T, PID) ASTORE((ARR) + (((size_t)(T) * 64 + lane) * 128) + (PID), 1u)

  if (blockIdx.x < 32) {
    // -------- layer 1: j-slice [bi*16,bi*16+16), wid = gate --------
    const int bi = blockIdx.x;
    const int pid = bi * 4 + wid;
    u16* hlds = (u16*)smem;                   // [32][520] u16
    float* glds = (float*)(smem + 33280);     // [4][32][17] f32

    bf16x8 wreg[16];
    const u16* wp = whh1 + (((size_t)(wid * 512 + bi * 16 + lo)) << 9) + hi * 8;
#pragma unroll
    for (int ks = 0; ks < 16; ++ks) wreg[ks] = *(const bf16x8*)(wp + ks * 32);

    float creg0 = 0.f, creg1 = 0.f;

    for (int t = 0; t < 63; ++t) {
      const float* pr = pre + (((size_t)(t * 32 + pb)) << 11) + bi * 16 + pj0;
      float pi0 = pr[0], pf0 = pr[512], pg0 = pr[1024], po0 = pr[1536];
      float pi1 = pr[1], pf1 = pr[513], pg1 = pr[1025], po1 = pr[1537];

      const u64* hp = (const u64*)(h1d + ((size_t)t * 32 + hrow) * 512);
      f32x4 acc0 = (f32x4){0.f,0.f,0.f,0.f}, acc1 = (f32x4){0.f,0.f,0.f,0.f};
      const uint32_t* mb1 = flg1 + ((size_t)t * 64 + cb) * 128;

      // group 0: producers 0..63 (j 0..255, ks 0..7)
      POLL1(mb1 + lane)
      {
        u64 v[8];
#pragma unroll
        for (int g = 0; g < 4; ++g) {
          int c = k8 + 8 * g;
          v[2*g]   = ALOAD(hp + 2 * c);
          v[2*g+1] = ALOAD(hp + 2 * c + 1);
        }
#pragma unroll
        for (int g = 0; g < 4; ++g) {
          int c = k8 + 8 * g;
          u64 w2[2] = { v[2*g], v[2*g+1] };
          *(uint4*)(hlds + hrow * 520 + c * 8) = *(const uint4*)w2;
        }
      }
      __syncthreads();
#pragma unroll
      for (int ks = 0; ks < 8; ++ks) {
        int cg = (ks * 4 + hi) * 8;
        bf16x8 a0 = *(const bf16x8*)(hlds + lo * 520 + cg);
        bf16x8 a1 = *(const bf16x8*)(hlds + (16 + lo) * 520 + cg);
        acc0 = __builtin_amdgcn_mfma_f32_16x16x32_bf16(a0, wreg[ks], acc0, 0, 0, 0);
        acc1 = __builtin_amdgcn_mfma_f32_16x16x32_bf16(a1, wreg[ks], acc1, 0, 0, 0);
      }
      // group 1: producers 64..127 (j 256..511, ks 8..15)
      POLL1(mb1 + 64 + lane)
      {
        u64 v[8];
#pragma unroll
        for (int g = 0; g < 4; ++g) {
          int c = 32 + k8 + 8 * g;
          v[2*g]   = ALOAD(hp + 2 * c);
          v[2*g+1] = ALOAD(hp + 2 * c + 1);
        }
#pragma unroll
        for (int g = 0; g < 4; ++g) {
          int c = 32 + k8 + 8 * g;
          u64 w2[2] = { v[2*g], v[2*g+1] };
          *(uint4*)(hlds + hrow * 520 + c * 8) = *(const uint4*)w2;
        }
      }
      __syncthreads();
#pragma unroll
      for (int ks = 8; ks < 16; ++ks) {
        int cg = (ks * 4 + hi) * 8;
        bf16x8 a0 = *(const bf16x8*)(hlds + lo * 520 + cg);
        bf16x8 a1 = *(const bf16x8*)(hlds + (16 + lo) * 520 + cg);
        acc0 = __builtin_amdgcn_mfma_f32_16x16x32_bf16(a0, wreg[ks], acc0, 0, 0, 0);
        acc1 = __builtin_amdgcn_mfma_f32_16x16x32_bf16(a1, wreg[ks], acc1, 0, 0, 0);
      }
      // gate exchange
#pragma unroll
      for (int r = 0; r < 4; ++r) {
        glds[wid * 544 + (hi * 4 + r) * 17 + lo] = acc0[r];
        glds[wid * 544 + (16 + hi * 4 + r) * 17 + lo] = acc1[r];
      }
      __syncthreads();

      float iv0 = glds[0*544 + pb*17 + pj0]   + pi0, fv0 = glds[1*544 + pb*17 + pj0]   + pf0;
      float gv0 = glds[2*544 + pb*17 + pj0]   + pg0, ov0 = glds[3*544 + pb*17 + pj0]   + po0;
      float iv1 = glds[0*544 + pb*17 + pj0+1] + pi1, fv1 = glds[1*544 + pb*17 + pj0+1] + pf1;
      float gv1 = glds[2*544 + pb*17 + pj0+1] + pg1, ov1 = glds[3*544 + pb*17 + pj0+1] + po1;
      float cn0 = fsig(fv0) * creg0 + fsig(iv0) * ftanh(gv0);
      float hn0 = fsig(ov0) * ftanh(cn0);
      float cn1 = fsig(fv1) * creg1 + fsig(iv1) * ftanh(gv1);
      float hn1 = fsig(ov1) * ftanh(cn1);
      creg0 = cn0; creg1 = cn1;
      ASTORE((uint32_t*)(h1d + ((size_t)(t + 1) * 32 + pb) * 512 + bi * 16 + pj0),
             pack2(hn0, hn1));
      WAVE_DRAIN();
      PUBF(flg1, t + 1, pid);
    }
  } else {
    // -------- layer 2: j-slice 16, wid = gate, K=1024 [h1|h2], split waits --------
    const int bi2 = blockIdx.x - 32;
    const int pid = bi2 * 4 + wid;
    u16* alds = (u16*)smem;                   // [32][1032] u16
    float* glds = (float*)(smem + 66048);     // [4][32][17] f32

    bf16x8 wreg[32];
    {
      const u16* wa = wih2 + (((size_t)(wid * 512 + bi2 * 16 + lo)) << 9) + hi * 8;
      const u16* wb = whh2 + (((size_t)(wid * 512 + bi2 * 16 + lo)) << 9) + hi * 8;
#pragma unroll
      for (int ks = 0; ks < 16; ++ks) {
        wreg[ks]      = *(const bf16x8*)(wa + ks * 32);
        wreg[16 + ks] = *(const bf16x8*)(wb + ks * 32);
      }
    }
    float bsv0 = bs2[0 * 512 + bi2 * 16 + pj0], bsv0b = bs2[0 * 512 + bi2 * 16 + pj0 + 1];
    float bsv1 = bs2[1 * 512 + bi2 * 16 + pj0], bsv1b = bs2[1 * 512 + bi2 * 16 + pj0 + 1];
    float bsv2 = bs2[2 * 512 + bi2 * 16 + pj0], bsv2b = bs2[2 * 512 + bi2 * 16 + pj0 + 1];
    float bsv3 = bs2[3 * 512 + bi2 * 16 + pj0], bsv3b = bs2[3 * 512 + bi2 * 16 + pj0 + 1];

    float creg0 = 0.f, creg1 = 0.f;

    for (int t = 0; t < 63; ++t) {
      f32x4 acc0 = (f32x4){0.f,0.f,0.f,0.f}, acc1 = (f32x4){0.f,0.f,0.f,0.f};
      const uint32_t* mbA = flg1 + ((size_t)(t + 1) * 64 + cb) * 128;
      const uint32_t* mbB = flg2 + ((size_t)t * 64 + cb) * 128;

      // phase A: h1[t+1] (usually ready early; L1 runs ahead)
      POLL2(mbA + lane, mbA + 64 + lane)
      {
        const u64* hp1 = (const u64*)(h1d + ((size_t)(t + 1) * 32 + hrow) * 512);
        u64 v[16];
#pragma unroll
        for (int g = 0; g < 8; ++g) {
          int c = k8 + 8 * g;
          v[2*g]   = ALOAD(hp1 + 2 * c);
          v[2*g+1] = ALOAD(hp1 + 2 * c + 1);
        }
#pragma unroll
        for (int g = 0; g < 8; ++g) {
          int c = k8 + 8 * g;
          u64 w2[2] = { v[2*g], v[2*g+1] };
          *(uint4*)(alds + hrow * 1032 + c * 8) = *(const uint4*)w2;
        }
      }
      __syncthreads();
#pragma unroll
      for (int ks = 0; ks < 16; ++ks) {
        int cg = (ks * 4 + hi) * 8;
        bf16x8 a0 = *(const bf16x8*)(alds + lo * 1032 + cg);
        bf16x8 a1 = *(const bf16x8*)(alds + (16 + lo) * 1032 + cg);
        acc0 = __builtin_amdgcn_mfma_f32_16x16x32_bf16(a0, wreg[ks], acc0, 0, 0, 0);
        acc1 = __builtin_amdgcn_mfma_f32_16x16x32_bf16(a1, wreg[ks], acc1, 0, 0, 0);
      }
      // phase B: h2[t] (self-chain critical tail)
      POLL2(mbB + lane, mbB + 64 + lane)
      {
        const u64* hp2 = (const u64*)(h2a + ((size_t)t * 32 + hrow) * 512);
        u64 v[16];
#pragma unroll
        for (int g = 0; g < 8; ++g) {
          int c = k8 + 8 * g;
          v[2*g]   = ALOAD(hp2 + 2 * c);
          v[2*g+1] = ALOAD(hp2 + 2 * c + 1);
        }
#pragma unroll
        for (int g = 0; g < 8; ++g) {
          int c = 64 + k8 + 8 * g;
          u64 w2[2] = { v[2*g], v[2*g+1] };
          *(uint4*)(alds + hrow * 1032 + c * 8) = *(const uint4*)w2;
        }
      }
      __syncthreads();
#pragma unroll
      for (int ks = 0; ks < 16; ++ks) {
        int cg = (64 + ks * 4 + hi) * 8;
        bf16x8 a0 = *(const bf16x8*)(alds + lo * 1032 + cg);
        bf16x8 a1 = *(const bf16x8*)(alds + (16 + lo) * 1032 + cg);
        acc0 = __builtin_amdgcn_mfma_f32_16x16x32_bf16(a0, wreg[16 + ks], acc0, 0, 0, 0);
        acc1 = __builtin_amdgcn_mfma_f32_16x16x32_bf16(a1, wreg[16 + ks], acc1, 0, 0, 0);
      }
#pragma unroll
      for (int r = 0; r < 4; ++r) {
        glds[wid * 544 + (hi * 4 + r) * 17 + lo] = acc0[r];
        glds[wid * 544 + (16 + hi * 4 + r) * 17 + lo] = acc1[r];
      }
      __syncthreads();

      float gi0 = glds[0*544 + pb*17 + pj0]   + bsv0,  gf0 = glds[1*544 + pb*17 + pj0]   + bsv1;
      float gg0 = glds[2*544 + pb*17 + pj0]   + bsv2,  go0 = glds[3*544 + pb*17 + pj0]   + bsv3;
      float gi1 = glds[0*544 + pb*17 + pj0+1] + bsv0b, gf1 = glds[1*544 + pb*17 + pj0+1] + bsv1b;
      float gg1 = glds[2*544 + pb*17 + pj0+1] + bsv2b, go1 = glds[3*544 + pb*17 + pj0+1] + bsv3b;
      float cn0 = fsig(gf0) * creg0 + fsig(gi0) * ftanh(gg0);
      float hn0 = fsig(go0) * ftanh(cn0);
      float cn1 = fsig(gf1) * creg1 + fsig(gi1) * ftanh(gg1);
      float hn1 = fsig(go1) * ftanh(cn1);
      creg0 = cn0; creg1 = cn1;
      ASTORE((uint32_t*)(h2a + ((size_t)(t + 1) * 32 + pb) * 512 + bi2 * 16 + pj0),
             pack2(hn0, hn1));
      WAVE_DRAIN();
      PUBF(flg2, t + 1, pid);
    }
  }
#undef POLL1
#undef POLL2
#undef PUBF
#undef WAVE_DRAIN
}

// ---------------- host ----------------
extern "C" void kernel_launch(void* const* d_in, const int* in_sizes, int n_in,
                              void* d_out, int out_size, void* d_ws, size_t ws_size,
                              hipStream_t stream) {
  const int*   src  = (const int*)  d_in[0];
  const int*   trg  = (const int*)  d_in[1];
  const float* eemb = (const float*)d_in[2];
  const float* demb = (const float*)d_in[3];
  const float* cw3  = (const float*)d_in[4];
  const float* cb3  = (const float*)d_in[5];
  const float* cw4  = (const float*)d_in[6];
  const float* cb4  = (const float*)d_in[7];
  const float* cw5  = (const float*)d_in[8];
  const float* cb5  = (const float*)d_in[9];
  const float* fc1w = (const float*)d_in[10];
  const float* fc1b = (const float*)d_in[11];
  const float* fc2w = (const float*)d_in[12];
  const float* fc2b = (const float*)d_in[13];
  const float* wih1 = (const float*)d_in[14];
  const float* whh1 = (const float*)d_in[15];
  const float* bih1 = (const float*)d_in[16];
  const float* bhh1 = (const float*)d_in[17];
  const float* wih2 = (const float*)d_in[18];
  const float* whh2 = (const float*)d_in[19];
  const float* bih2 = (const float*)d_in[20];
  const float* bhh2 = (const float*)d_in[21];
  const float* outw = (const float*)d_in[22];
  const float* outb = (const float*)d_in[23];
  float* out = (float*)d_out;

  // ---- ws carve ----
  uint32_t* flg1 = (uint32_t*)d_ws;           // 64*64*128 = 524,288 u32 (2MB)
  uint32_t* flg2 = flg1 + 524288;             // 524,288
  u16* h1d      = (u16*)(flg2 + 524288);      // 1,048,576 u16
  u16* h2a      = h1d + 1048576;              // 1,048,576
  float* pooled = (float*)(h2a + 1048576);    // 24576
  float* ench   = pooled + 24576;             // 16384
  float* enco   = ench + 16384;               // 16384
  float* bs1    = enco + 16384;               // 2048
  float* bs2    = bs1 + 2048;                 // 2048
  float* pre    = bs2 + 2048;                 // 4,128,768
  u16* outw_bf  = (u16*)(pre + 4128768);      // 16,384,000
  u16* wih1_bf  = outw_bf + 16384000;         // 1,572,864
  u16* wih2_bf  = wih1_bf + 1572864;          // 1,048,576
  u16* whh1_bf  = wih2_bf + 1048576;          // 1,048,576
  u16* whh2_bf  = whh1_bf + 1048576;          // 1,048,576
  u16* wtj3     = whh2_bf + 1048576;          // 196,608
  u16* wtj4     = wtj3 + 196608;              // 262,144
  u16* wtj5     = wtj4 + 262144;              // 327,680
  u16* X1       = wtj5 + 327680;              // 1,572,864

  init_all<<<512, 256, 0, stream>>>(pooled, flg1, flg2, h1d, h2a,
                                    bih1, bhh1, bih2, bhh2, bs1, bs2, out);
  cvt_all<<<2048, 256, 0, stream>>>(outw, outw_bf, wih1, wih1_bf, wih2, wih2_bf,
                                    whh1, whh1_bf, whh2, whh2_bf);
  wtj_all<<<512, 256, 0, stream>>>(cw3, wtj3, cw4, wtj4, cw5, wtj5);

  conv_mfma<<<dim3(128, 2, 3), 256, 0, stream>>>(wtj3, wtj4, wtj5, cb3, cb4, cb5,
                                                 pooled, src, eemb);
  gemm_small<<<64, 256, 0, stream>>>(pooled, fc1w, fc1b, ench, 768, 512, 1);
  gemm_small<<<64, 256, 0, stream>>>(ench, fc2w, fc2b, enco, 512, 512, 0);

  build_x1<<<2048, 256, 0, stream>>>(trg, demb, enco, X1);
  gemm_mfma<0><<<dim3(16, 16), 256, 0, stream>>>(X1, wih1_bf, bs1, pre, 2016, 2048, 768);
  lstm_fused<<<64, 256, 0, stream>>>(pre, whh1_bf, wih2_bf, whh2_bf, bs2,
                                     flg1, flg2, h1d, h2a);
  gemm_mfma<1><<<dim3(16, 250), 256, 0, stream>>>(h2a + 16384, outw_bf, outb, out,
                                                  2016, V_, 512);
}

// Round 8
// 471.332 us; speedup vs baseline: 1.1817x; 1.1817x over previous
//
#include <hip/hip_runtime.h>
#include <math.h>
#include <stdint.h>

#define B_    32
#define E_    256
#define F_    256
#define H_    512
#define V_    32000
#define G4    2048

typedef unsigned short u16;
typedef unsigned long long u64;
typedef __attribute__((ext_vector_type(8))) short bf16x8;
typedef __attribute__((ext_vector_type(4))) float f32x4;

__device__ __forceinline__ float fsig(float x) {   // 1/(1+e^-x), v_exp+v_rcp
  return __builtin_amdgcn_rcpf(1.f + __expf(-x));
}
__device__ __forceinline__ float ftanh(float x) {  // 1 - 2/(e^2x+1)
  return 1.f - 2.f * __builtin_amdgcn_rcpf(1.f + __expf(2.f * x));
}

__device__ __forceinline__ u16 f2bf(float f) {
  uint32_t u = __float_as_uint(f);
  uint32_t r = (u + 0x7FFFu + ((u >> 16) & 1u)) >> 16;   // RNE
  return (u16)r;
}
__device__ __forceinline__ uint32_t pack2(float a, float b) {
  return (uint32_t)f2bf(a) | ((uint32_t)f2bf(b) << 16);
}

#define GLOAD16(gp, lp) __builtin_amdgcn_global_load_lds( \
    (const __attribute__((address_space(1))) uint32_t*)(const void*)(gp), \
    (__attribute__((address_space(3))) uint32_t*)(void*)(lp), 16, 0, 0)

#define ALOAD(P) __hip_atomic_load((P), __ATOMIC_RELAXED, __HIP_MEMORY_SCOPE_AGENT)
#define ASTORE(P, V) __hip_atomic_store((P), (V), __ATOMIC_RELAXED, __HIP_MEMORY_SCOPE_AGENT)

// ---------------- fused init (R6 flag layout: [64 t][128 producer] 64B-padded) -------
__global__ void init_all(float* pooled, uint32_t* sent1, uint32_t* sent2,
                         u16* h1d, u16* h2a,
                         const float* bi1, const float* bh1,
                         const float* bi2, const float* bh2,
                         float* bs1, float* bs2, float* out) {
  int i = blockIdx.x * blockDim.x + threadIdx.x, st = gridDim.x * blockDim.x;
  for (int k = i; k < 24576; k += st) pooled[k] = 0.f;
  for (int k = i; k < 131072; k += st) {
    uint32_t v = (k < 2048 && (k & 15) == 0) ? 1u : 0u;   // t=0 ready
    sent1[k] = v; sent2[k] = v;
  }
  uint4 z = {0u, 0u, 0u, 0u};
  for (int k = i; k < 2048; k += st) { ((uint4*)h1d)[k] = z; ((uint4*)h2a)[k] = z; }
  for (int k = i; k < G4; k += st) { bs1[k] = bi1[k] + bh1[k]; bs2[k] = bi2[k] + bh2[k]; }
  for (int k = i; k < B_ * V_; k += st) {
    int b = k / V_, v = k - b * V_;
    out[(size_t)b * 64 * V_ + v] = 0.f;
  }
}

// ---------------- fused bf16 conversion of 5 weight tensors --------------------------
__global__ void cvt_all(const float* s0, u16* d0, const float* s1, u16* d1,
                        const float* s2, u16* d2, const float* s3, u16* d3,
                        const float* s4, u16* d4) {
  int i = blockIdx.x * blockDim.x + threadIdx.x, st = gridDim.x * blockDim.x;
  for (; i < 2637824; i += st) {
    int j = i; const float* s; u16* d;
    if (j < 2048000) { s = s0; d = d0; }
    else if ((j -= 2048000) < 196608) { s = s1; d = d1; }
    else if ((j -= 196608) < 131072) { s = s2; d = d2; }
    else if ((j -= 131072) < 131072) { s = s3; d = d3; }
    else { j -= 131072; s = s4; d = d4; }
    const float4* sp = (const float4*)s + 2 * (size_t)j;
    float4 a = sp[0], b = sp[1];
    uint4 u;
    u.x = pack2(a.x, a.y); u.y = pack2(a.z, a.w);
    u.z = pack2(b.x, b.y); u.w = pack2(b.z, b.w);
    *((uint4*)d + j) = u;
  }
}

// conv weights (F,E,kw) -> bf16 [f][j*256+e], all 3 in one kernel
__global__ void wtj_all(const float* w3, u16* t3, const float* w4, u16* t4,
                        const float* w5, u16* t5) {
  int i = blockIdx.x * blockDim.x + threadIdx.x, st = gridDim.x * blockDim.x;
  for (; i < 786432; i += st) {
    int j = i; const float* w; u16* wt; int kw;
    if (j < 196608) { w = w3; wt = t3; kw = 3; }
    else if ((j -= 196608) < 262144) { w = w4; wt = t4; kw = 4; }
    else { j -= 262144; w = w5; wt = t5; kw = 5; }
    int f = j / (kw * 256);
    int r = j - f * (kw * 256);
    int jj = r >> 8, e = r & 255;
    wt[j] = f2bf(w[(f * 256 + e) * kw + jj]);
  }
}

// X1 rows (bf16): [dec_emb(tok) | enc_out], rows r=t*32+b, pad rows zeroed
__global__ void build_x1(const int* __restrict__ trg, const float* __restrict__ demb,
                         const float* __restrict__ enco, u16* __restrict__ X1) {
  int r = blockIdx.x, tid = threadIdx.x;
  u16* row = X1 + (size_t)r * 768;
  if (r >= 2016) { row[tid] = 0; row[256 + tid] = 0; row[512 + tid] = 0; return; }
  int t = r >> 5, b = r & 31;
  int tok = trg[b * 64 + t];
  row[tid]       = f2bf(demb[(size_t)tok * E_ + tid]);
  row[256 + tid] = f2bf(enco[b * H_ + tid]);
  row[512 + tid] = f2bf(enco[b * H_ + 256 + tid]);
}

// ---------------- small fp32 GEMM (fc1/fc2) ----------------
__global__ void gemm_small(const float* __restrict__ A, const float* __restrict__ W,
                           const float* __restrict__ bias, float* __restrict__ C,
                           int K, int N, int relu) {
  int nl = threadIdx.x & 7, b = threadIdx.x >> 3;
  int n = blockIdx.x * 8 + nl;
  const float* a = A + b * K;
  const float* w = W + (size_t)n * K;
  float acc = 0.f;
  for (int k = 0; k < K; k += 4) {
    float4 av = *reinterpret_cast<const float4*>(&a[k]);
    float4 wv = *reinterpret_cast<const float4*>(&w[k]);
    acc = fmaf(av.x, wv.x, acc); acc = fmaf(av.y, wv.y, acc);
    acc = fmaf(av.z, wv.z, acc); acc = fmaf(av.w, wv.w, acc);
  }
  acc += bias[n];
  if (relu) acc = fmaxf(acc, 0.f);
  C[b * N + n] = acc;
}

// ---------------- bf16 MFMA GEMM, 128x128 tile, BK=32, double-buffered --------------
__global__ __launch_bounds__(256)
void gemm_mfma(const u16* __restrict__ A, const u16* __restrict__ Bw,
               const float* __restrict__ bias, float* __restrict__ C,
               int M, int N, int K) {
  __shared__ char smem[32768];
  const int tid = threadIdx.x;
  const int wid = tid >> 6, lane = tid & 63;
  const int hi = lane >> 4, lo = lane & 15;
  const int wr = wid >> 1, wc = wid & 1;
  const int m0 = blockIdx.x * 128, n0 = blockIdx.y * 128;
  const int NT = K >> 5;
  const int srow = lane >> 2, sc = lane & 3;

  f32x4 acc[4][4];
#pragma unroll
  for (int i = 0; i < 4; ++i)
#pragma unroll
    for (int j = 0; j < 4; ++j) acc[i][j] = (f32x4){0.f, 0.f, 0.f, 0.f};

  for (int t = -1; t < NT; ++t) {
    int ts = t + 1;
    if (ts < NT) {
      char* base = smem + (ts & 1) * 16384;
      int k0 = ts << 5;
#pragma unroll
      for (int q = 0; q < 2; ++q) {
        int row = (wid + q * 4) * 16 + srow;
        int gc = sc ^ (row & 3);
        const char* gp = (const char*)A + (((size_t)(m0 + row) * K + k0) << 1) + gc * 16;
        GLOAD16(gp, base + (wid + q * 4) * 1024);
      }
#pragma unroll
      for (int q = 0; q < 2; ++q) {
        int row = (wid + q * 4) * 16 + srow;
        int gc = sc ^ (row & 3);
        const char* gp = (const char*)Bw + (((size_t)(n0 + row) * K + k0) << 1) + gc * 16;
        GLOAD16(gp, base + 8192 + (wid + q * 4) * 1024);
      }
    }
    if (t >= 0) {
      char* base = smem + (t & 1) * 16384;
      bf16x8 af[4], bfr[4];
#pragma unroll
      for (int mi = 0; mi < 4; ++mi) {
        int row = wr * 64 + mi * 16 + lo;
        af[mi] = *(const bf16x8*)(base + row * 64 + ((hi ^ (row & 3)) << 4));
      }
#pragma unroll
      for (int ni = 0; ni < 4; ++ni) {
        int row = wc * 64 + ni * 16 + lo;
        bfr[ni] = *(const bf16x8*)(base + 8192 + row * 64 + ((hi ^ (row & 3)) << 4));
      }
#pragma unroll
      for (int mi = 0; mi < 4; ++mi)
#pragma unroll
        for (int ni = 0; ni < 4; ++ni)
          acc[mi][ni] = __builtin_amdgcn_mfma_f32_16x16x32_bf16(af[mi], bfr[ni], acc[mi][ni], 0, 0, 0);
    }
    __syncthreads();
  }

#pragma unroll
  for (int mi = 0; mi < 4; ++mi)
#pragma unroll
    for (int r = 0; r < 4; ++r) {
      int m = m0 + wr * 64 + mi * 16 + hi * 4 + r;
      if (m >= M) continue;
      size_t rowbase = (size_t)m * N;
#pragma unroll
      for (int ni = 0; ni < 4; ++ni) {
        int col = n0 + wc * 64 + ni * 16 + lo;
        C[rowbase + col] = acc[mi][ni][r] + bias[col];
      }
    }
}

// ---------------- conv via implicit im2col + fused relu/maxpool, z = filter set ------
__global__ __launch_bounds__(256)
void conv_mfma(const u16* __restrict__ wt3, const u16* __restrict__ wt4,
               const u16* __restrict__ wt5,
               const float* __restrict__ cb3, const float* __restrict__ cb4,
               const float* __restrict__ cb5,
               float* __restrict__ pooled,
               const int* __restrict__ srcTok, const float* __restrict__ emb) {
  const int z = blockIdx.z;
  const u16* Bw = (z == 0) ? wt3 : (z == 1) ? wt4 : wt5;
  const float* bias = (z == 0) ? cb3 : (z == 1) ? cb4 : cb5;
  const int K = 768 + 256 * z, kw = 3 + z, poolOff = 256 * z;

  __shared__ char smem[32768];
  const int tid = threadIdx.x;
  const int wid = tid >> 6, lane = tid & 63;
  const int hi = lane >> 4, lo = lane & 15;
  const int wr = wid >> 1, wc = wid & 1;
  const int m0 = blockIdx.x * 128, n0 = blockIdx.y * 128;
  const int NT = K >> 5;
  const int srow = lane >> 2, sc = lane & 3;

  f32x4 acc[4][4];
#pragma unroll
  for (int i = 0; i < 4; ++i)
#pragma unroll
    for (int j = 0; j < 4; ++j) acc[i][j] = (f32x4){0.f, 0.f, 0.f, 0.f};

  for (int t = -1; t < NT; ++t) {
    int ts = t + 1;
    if (ts < NT) {
      char* base = smem + (ts & 1) * 16384;
      int k0 = ts << 5;
      {  // A: gather from embeddings (im2col in LDS)
        int j = k0 >> 8, e0 = k0 & 255;
        int row = tid >> 1;
        int m = m0 + row;
        int s = m & 511, b = m >> 9;
        int sj = s + j;
        int tok = (sj < 512) ? srcTok[b * 512 + sj] : -1;
#pragma unroll
        for (int q = 0; q < 2; ++q) {
          int cg = (tid & 1) * 2 + q;
          uint4 u;
          if (tok >= 0) {
            const float* ep = emb + (size_t)tok * 256 + e0 + cg * 8;
            float4 f0 = *(const float4*)(ep);
            float4 f1 = *(const float4*)(ep + 4);
            u.x = pack2(f0.x, f0.y); u.y = pack2(f0.z, f0.w);
            u.z = pack2(f1.x, f1.y); u.w = pack2(f1.z, f1.w);
          } else u = (uint4){0, 0, 0, 0};
          int c = cg ^ (row & 3);
          *(uint4*)(base + row * 64 + c * 16) = u;
        }
      }
#pragma unroll
      for (int q = 0; q < 2; ++q) {
        int row = (wid + q * 4) * 16 + srow;
        int gc = sc ^ (row & 3);
        const char* gp = (const char*)Bw + (((size_t)(n0 + row) * K + k0) << 1) + gc * 16;
        GLOAD16(gp, base + 8192 + (wid + q * 4) * 1024);
      }
    }
    if (t >= 0) {
      char* base = smem + (t & 1) * 16384;
      bf16x8 af[4], bfr[4];
#pragma unroll
      for (int mi = 0; mi < 4; ++mi) {
        int row = wr * 64 + mi * 16 + lo;
        af[mi] = *(const bf16x8*)(base + row * 64 + ((hi ^ (row & 3)) << 4));
      }
#pragma unroll
      for (int ni = 0; ni < 4; ++ni) {
        int row = wc * 64 + ni * 16 + lo;
        bfr[ni] = *(const bf16x8*)(base + 8192 + row * 64 + ((hi ^ (row & 3)) << 4));
      }
#pragma unroll
      for (int mi = 0; mi < 4; ++mi)
#pragma unroll
        for (int ni = 0; ni < 4; ++ni)
          acc[mi][ni] = __builtin_amdgcn_mfma_f32_16x16x32_bf16(af[mi], bfr[ni], acc[mi][ni], 0, 0, 0);
    }
    __syncthreads();
  }

  int b = m0 >> 9;
  int slim = 512 - kw;
#pragma unroll
  for (int ni = 0; ni < 4; ++ni) {
    int col = n0 + wc * 64 + ni * 16 + lo;
    float bv = bias[col];
    float mx = 0.f;
#pragma unroll
    for (int mi = 0; mi < 4; ++mi)
#pragma unroll
      for (int r = 0; r < 4; ++r) {
        int m = m0 + wr * 64 + mi * 16 + hi * 4 + r;
        int s = m & 511;
        float v = acc[mi][ni][r] + bv;
        if (s <= slim && v > mx) mx = v;
      }
    atomicMax((int*)&pooled[b * 768 + poolOff + col], __float_as_int(mx));
  }
}

// ---------------- fused persistent kernel: 2-layer LSTM + overlapped out-GEMM --------
// Blocks 0..31: layer-1. Blocks 32..63: layer-2. Blocks 64..223: out-projection,
// consuming h2 slots as flags appear (in-order publication => flag t' covers <=t').
// lstm protocol = R6 (best measured): shared sentinel flags, all-wave polls, wave
// drain before lane0 flag store. Out blocks slow-poll (s_sleep 16, wid0 only) to
// keep poll pressure off the critical flag lines.
__global__ __launch_bounds__(256, 1)
void lstm_fused(const float* __restrict__ pre,
                const u16* __restrict__ whh1,
                const u16* __restrict__ wih2, const u16* __restrict__ whh2,
                const float* __restrict__ bs2,
                uint32_t* __restrict__ sent1, uint32_t* __restrict__ sent2,
                u16* __restrict__ h1d, u16* __restrict__ h2a,
                const u16* __restrict__ outw_bf, const float* __restrict__ outb,
                float* __restrict__ out) {
  __shared__ char smem[74752];
  const int tid = threadIdx.x;
  const int wid = tid >> 6, lane = tid & 63, hi = lane >> 4, lo = lane & 15;
  const int hrow = tid >> 3, k8 = tid & 7;
  const int pb = hrow, pj0 = k8 * 2;

#define WAVE_DRAIN() asm volatile("s_waitcnt vmcnt(0)" ::: "memory")
#define POLL1(P) while (ALOAD(P) == 0u) __builtin_amdgcn_s_sleep(1);
#define POLL2(P, Q) for (;;) { uint32_t x_ = ALOAD(P), y_ = ALOAD(Q); \
                               if (x_ & y_) break; __builtin_amdgcn_s_sleep(1); }
#define POLL2S(P, Q) for (;;) { uint32_t x_ = ALOAD(P), y_ = ALOAD(Q); \
                                if (x_ & y_) break; __builtin_amdgcn_s_sleep(16); }

  if (blockIdx.x < 32) {
    // -------- layer 1: j-slice [bi*16,bi*16+16), wid = gate --------
    const int bi = blockIdx.x;
    u16* hlds = (u16*)smem;                   // [32][520] u16
    float* glds = (float*)(smem + 33280);     // [4][32][17] f32

    bf16x8 wreg[16];
    const u16* wp = whh1 + (((size_t)(wid * 512 + bi * 16 + lo)) << 9) + hi * 8;
#pragma unroll
    for (int ks = 0; ks < 16; ++ks) wreg[ks] = *(const bf16x8*)(wp + ks * 32);

    float creg0 = 0.f, creg1 = 0.f;

    for (int t = 0; t < 63; ++t) {
      const float* pr = pre + (((size_t)(t * 32 + pb)) << 11) + bi * 16 + pj0;
      float pi0 = pr[0], pf0 = pr[512], pg0 = pr[1024], po0 = pr[1536];
      float pi1 = pr[1], pf1 = pr[513], pg1 = pr[1025], po1 = pr[1537];

      const u64* hp = (const u64*)(h1d + ((size_t)t * 32 + hrow) * 512);
      f32x4 acc0 = (f32x4){0.f,0.f,0.f,0.f}, acc1 = (f32x4){0.f,0.f,0.f,0.f};

      // group 0: producers 0..63 (j 0..255, ks 0..7)
      POLL1(sent1 + (size_t)t * 2048 + lane * 16)
      {
        u64 v[8];
#pragma unroll
        for (int g = 0; g < 4; ++g) {
          int c = k8 + 8 * g;
          v[2*g]   = ALOAD(hp + 2 * c);
          v[2*g+1] = ALOAD(hp + 2 * c + 1);
        }
#pragma unroll
        for (int g = 0; g < 4; ++g) {
          int c = k8 + 8 * g;
          u64 w2[2] = { v[2*g], v[2*g+1] };
          *(uint4*)(hlds + hrow * 520 + c * 8) = *(const uint4*)w2;
        }
      }
      __syncthreads();
#pragma unroll
      for (int ks = 0; ks < 8; ++ks) {
        int cg = (ks * 4 + hi) * 8;
        bf16x8 a0 = *(const bf16x8*)(hlds + lo * 520 + cg);
        bf16x8 a1 = *(const bf16x8*)(hlds + (16 + lo) * 520 + cg);
        acc0 = __builtin_amdgcn_mfma_f32_16x16x32_bf16(a0, wreg[ks], acc0, 0, 0, 0);
        acc1 = __builtin_amdgcn_mfma_f32_16x16x32_bf16(a1, wreg[ks], acc1, 0, 0, 0);
      }
      // group 1: producers 64..127 (j 256..511, ks 8..15)
      POLL1(sent1 + (size_t)t * 2048 + (64 + lane) * 16)
      {
        u64 v[8];
#pragma unroll
        for (int g = 0; g < 4; ++g) {
          int c = 32 + k8 + 8 * g;
          v[2*g]   = ALOAD(hp + 2 * c);
          v[2*g+1] = ALOAD(hp + 2 * c + 1);
        }
#pragma unroll
        for (int g = 0; g < 4; ++g) {
          int c = 32 + k8 + 8 * g;
          u64 w2[2] = { v[2*g], v[2*g+1] };
          *(uint4*)(hlds + hrow * 520 + c * 8) = *(const uint4*)w2;
        }
      }
      __syncthreads();
#pragma unroll
      for (int ks = 8; ks < 16; ++ks) {
        int cg = (ks * 4 + hi) * 8;
        bf16x8 a0 = *(const bf16x8*)(hlds + lo * 520 + cg);
        bf16x8 a1 = *(const bf16x8*)(hlds + (16 + lo) * 520 + cg);
        acc0 = __builtin_amdgcn_mfma_f32_16x16x32_bf16(a0, wreg[ks], acc0, 0, 0, 0);
        acc1 = __builtin_amdgcn_mfma_f32_16x16x32_bf16(a1, wreg[ks], acc1, 0, 0, 0);
      }
      // gate exchange
#pragma unroll
      for (int r = 0; r < 4; ++r) {
        glds[wid * 544 + (hi * 4 + r) * 17 + lo] = acc0[r];
        glds[wid * 544 + (16 + hi * 4 + r) * 17 + lo] = acc1[r];
      }
      __syncthreads();

      float iv0 = glds[0*544 + pb*17 + pj0]   + pi0, fv0 = glds[1*544 + pb*17 + pj0]   + pf0;
      float gv0 = glds[2*544 + pb*17 + pj0]   + pg0, ov0 = glds[3*544 + pb*17 + pj0]   + po0;
      float iv1 = glds[0*544 + pb*17 + pj0+1] + pi1, fv1 = glds[1*544 + pb*17 + pj0+1] + pf1;
      float gv1 = glds[2*544 + pb*17 + pj0+1] + pg1, ov1 = glds[3*544 + pb*17 + pj0+1] + po1;
      float cn0 = fsig(fv0) * creg0 + fsig(iv0) * ftanh(gv0);
      float hn0 = fsig(ov0) * ftanh(cn0);
      float cn1 = fsig(fv1) * creg1 + fsig(iv1) * ftanh(gv1);
      float hn1 = fsig(ov1) * ftanh(cn1);
      creg0 = cn0; creg1 = cn1;
      ASTORE((uint32_t*)(h1d + ((size_t)(t + 1) * 32 + pb) * 512 + bi * 16 + pj0),
             pack2(hn0, hn1));
      WAVE_DRAIN();
      if (lane == 0)
        ASTORE(sent1 + (size_t)(t + 1) * 2048 + (bi * 4 + wid) * 16, 1u);
    }
  } else if (blockIdx.x < 64) {
    // -------- layer 2: j-slice 16, wid = gate, K=1024 [h1|h2], split waits --------
    const int bi2 = blockIdx.x - 32;
    u16* alds = (u16*)smem;                   // [32][1032] u16
    float* glds = (float*)(smem + 66048);     // [4][32][17] f32

    bf16x8 wreg[32];
    {
      const u16* wa = wih2 + (((size_t)(wid * 512 + bi2 * 16 + lo)) << 9) + hi * 8;
      const u16* wb = whh2 + (((size_t)(wid * 512 + bi2 * 16 + lo)) << 9) + hi * 8;
#pragma unroll
      for (int ks = 0; ks < 16; ++ks) {
        wreg[ks]      = *(const bf16x8*)(wa + ks * 32);
        wreg[16 + ks] = *(const bf16x8*)(wb + ks * 32);
      }
    }
    float bsv0 = bs2[0 * 512 + bi2 * 16 + pj0], bsv0b = bs2[0 * 512 + bi2 * 16 + pj0 + 1];
    float bsv1 = bs2[1 * 512 + bi2 * 16 + pj0], bsv1b = bs2[1 * 512 + bi2 * 16 + pj0 + 1];
    float bsv2 = bs2[2 * 512 + bi2 * 16 + pj0], bsv2b = bs2[2 * 512 + bi2 * 16 + pj0 + 1];
    float bsv3 = bs2[3 * 512 + bi2 * 16 + pj0], bsv3b = bs2[3 * 512 + bi2 * 16 + pj0 + 1];

    float creg0 = 0.f, creg1 = 0.f;

    for (int t = 0; t < 63; ++t) {
      f32x4 acc0 = (f32x4){0.f,0.f,0.f,0.f}, acc1 = (f32x4){0.f,0.f,0.f,0.f};

      // phase A: h1[t+1] (usually ready early; L1 runs ahead)
      POLL2(sent1 + (size_t)(t + 1) * 2048 + lane * 16,
            sent1 + (size_t)(t + 1) * 2048 + (64 + lane) * 16)
      {
        const u64* hp1 = (const u64*)(h1d + ((size_t)(t + 1) * 32 + hrow) * 512);
        u64 v[16];
#pragma unroll
        for (int g = 0; g < 8; ++g) {
          int c = k8 + 8 * g;
          v[2*g]   = ALOAD(hp1 + 2 * c);
          v[2*g+1] = ALOAD(hp1 + 2 * c + 1);
        }
#pragma unroll
        for (int g = 0; g < 8; ++g) {
          int c = k8 + 8 * g;
          u64 w2[2] = { v[2*g], v[2*g+1] };
          *(uint4*)(alds + hrow * 1032 + c * 8) = *(const uint4*)w2;
        }
      }
      __syncthreads();
#pragma unroll
      for (int ks = 0; ks < 16; ++ks) {
        int cg = (ks * 4 + hi) * 8;
        bf16x8 a0 = *(const bf16x8*)(alds + lo * 1032 + cg);
        bf16x8 a1 = *(const bf16x8*)(alds + (16 + lo) * 1032 + cg);
        acc0 = __builtin_amdgcn_mfma_f32_16x16x32_bf16(a0, wreg[ks], acc0, 0, 0, 0);
        acc1 = __builtin_amdgcn_mfma_f32_16x16x32_bf16(a1, wreg[ks], acc1, 0, 0, 0);
      }
      // phase B: h2[t] (self-chain critical tail)
      POLL2(sent2 + (size_t)t * 2048 + lane * 16,
            sent2 + (size_t)t * 2048 + (64 + lane) * 16)
      {
        const u64* hp2 = (const u64*)(h2a + ((size_t)t * 32 + hrow) * 512);
        u64 v[16];
#pragma unroll
        for (int g = 0; g < 8; ++g) {
          int c = k8 + 8 * g;
          v[2*g]   = ALOAD(hp2 + 2 * c);
          v[2*g+1] = ALOAD(hp2 + 2 * c + 1);
        }
#pragma unroll
        for (int g = 0; g < 8; ++g) {
          int c = 64 + k8 + 8 * g;
          u64 w2[2] = { v[2*g], v[2*g+1] };
          *(uint4*)(alds + hrow * 1032 + c * 8) = *(const uint4*)w2;
        }
      }
      __syncthreads();
#pragma unroll
      for (int ks = 0; ks < 16; ++ks) {
        int cg = (64 + ks * 4 + hi) * 8;
        bf16x8 a0 = *(const bf16x8*)(alds + lo * 1032 + cg);
        bf16x8 a1 = *(const bf16x8*)(alds + (16 + lo) * 1032 + cg);
        acc0 = __builtin_amdgcn_mfma_f32_16x16x32_bf16(a0, wreg[16 + ks], acc0, 0, 0, 0);
        acc1 = __builtin_amdgcn_mfma_f32_16x16x32_bf16(a1, wreg[16 + ks], acc1, 0, 0, 0);
      }
#pragma unroll
      for (int r = 0; r < 4; ++r) {
        glds[wid * 544 + (hi * 4 + r) * 17 + lo] = acc0[r];
        glds[wid * 544 + (16 + hi * 4 + r) * 17 + lo] = acc1[r];
      }
      __syncthreads();

      float gi0 = glds[0*544 + pb*17 + pj0]   + bsv0,  gf0 = glds[1*544 + pb*17 + pj0]   + bsv1;
      float gg0 = glds[2*544 + pb*17 + pj0]   + bsv2,  go0 = glds[3*544 + pb*17 + pj0]   + bsv3;
      float gi1 = glds[0*544 + pb*17 + pj0+1] + bsv0b, gf1 = glds[1*544 + pb*17 + pj0+1] + bsv1b;
      float gg1 = glds[2*544 + pb*17 + pj0+1] + bsv2b, go1 = glds[3*544 + pb*17 + pj0+1] + bsv3b;
      float cn0 = fsig(gf0) * creg0 + fsig(gi0) * ftanh(gg0);
      float hn0 = fsig(go0) * ftanh(cn0);
      float cn1 = fsig(gf1) * creg1 + fsig(gi1) * ftanh(gg1);
      float hn1 = fsig(go1) * ftanh(cn1);
      creg0 = cn0; creg1 = cn1;
      ASTORE((uint32_t*)(h2a + ((size_t)(t + 1) * 32 + pb) * 512 + bi2 * 16 + pj0),
             pack2(hn0, hn1));
      WAVE_DRAIN();
      if (lane == 0)
        ASTORE(sent2 + (size_t)(t + 1) * 2048 + (bi2 * 4 + wid) * 16, 1u);
    }
  } else {
    // -------- out-projection: persistent tiles over (rt 0..15, ct 0..249) --------
    const int bid2 = blockIdx.x - 64;             // 0..159
    const int wr = wid >> 1, wc = wid & 1;
    const int srow = lane >> 2, sc = lane & 3;
    const u16* A = h2a + 16384;                   // row r -> slot (r>>5)+1

    for (int w = bid2; w < 16 * 250; w += 160) {
      int rt = w / 250, ct = w - rt * 250;
      int tf = rt * 4 + 4; if (tf > 63) tf = 63;  // in-order flags cover slots <= tf
      if (wid == 0)
        POLL2S(sent2 + (size_t)tf * 2048 + lane * 16,
               sent2 + (size_t)tf * 2048 + (64 + lane) * 16)
      __syncthreads();

      const int m0 = rt * 128, n0 = ct * 128;
      f32x4 acc[4][4];
#pragma unroll
      for (int i = 0; i < 4; ++i)
#pragma unroll
        for (int j = 0; j < 4; ++j) acc[i][j] = (f32x4){0.f, 0.f, 0.f, 0.f};

      for (int t = -1; t < 16; ++t) {
        int ts = t + 1;
        if (ts < 16) {
          char* base = smem + (ts & 1) * 16384;
          int k0 = ts << 5;
#pragma unroll
          for (int q = 0; q < 2; ++q) {
            int row = (wid + q * 4) * 16 + srow;
            int gc = sc ^ (row & 3);
            const char* gp = (const char*)A + (((size_t)(m0 + row) * 512 + k0) << 1) + gc * 16;
            GLOAD16(gp, base + (wid + q * 4) * 1024);
          }
#pragma unroll
          for (int q = 0; q < 2; ++q) {
            int row = (wid + q * 4) * 16 + srow;
            int gc = sc ^ (row & 3);
            const char* gp = (const char*)outw_bf + (((size_t)(n0 + row) * 512 + k0) << 1) + gc * 16;
            GLOAD16(gp, base + 8192 + (wid + q * 4) * 1024);
          }
        }
        if (t >= 0) {
          char* base = smem + (t & 1) * 16384;
          bf16x8 af[4], bfr[4];
#pragma unroll
          for (int mi = 0; mi < 4; ++mi) {
            int row = wr * 64 + mi * 16 + lo;
            af[mi] = *(const bf16x8*)(base + row * 64 + ((hi ^ (row & 3)) << 4));
          }
#pragma unroll
          for (int ni = 0; ni < 4; ++ni) {
            int row = wc * 64 + ni * 16 + lo;
            bfr[ni] = *(const bf16x8*)(base + 8192 + row * 64 + ((hi ^ (row & 3)) << 4));
          }
#pragma unroll
          for (int mi = 0; mi < 4; ++mi)
#pragma unroll
            for (int ni = 0; ni < 4; ++ni)
              acc[mi][ni] = __builtin_amdgcn_mfma_f32_16x16x32_bf16(af[mi], bfr[ni], acc[mi][ni], 0, 0, 0);
        }
        __syncthreads();
      }

#pragma unroll
      for (int mi = 0; mi < 4; ++mi)
#pragma unroll
        for (int r = 0; r < 4; ++r) {
          int m = m0 + wr * 64 + mi * 16 + hi * 4 + r;
          if (m >= 2016) continue;
          int t2 = m >> 5, b = m & 31;
          size_t rowbase = ((size_t)b * 64 + t2 + 1) * (size_t)V_;
#pragma unroll
          for (int ni = 0; ni < 4; ++ni) {
            int col = n0 + wc * 64 + ni * 16 + lo;
            out[rowbase + col] = acc[mi][ni][r] + outb[col];
          }
        }
    }
  }
#undef POLL1
#undef POLL2
#undef POLL2S
#undef WAVE_DRAIN
}

// ---------------- host ----------------
extern "C" void kernel_launch(void* const* d_in, const int* in_sizes, int n_in,
                              void* d_out, int out_size, void* d_ws, size_t ws_size,
                              hipStream_t stream) {
  const int*   src  = (const int*)  d_in[0];
  const int*   trg  = (const int*)  d_in[1];
  const float* eemb = (const float*)d_in[2];
  const float* demb = (const float*)d_in[3];
  const float* cw3  = (const float*)d_in[4];
  const float* cb3  = (const float*)d_in[5];
  const float* cw4  = (const float*)d_in[6];
  const float* cb4  = (const float*)d_in[7];
  const float* cw5  = (const float*)d_in[8];
  const float* cb5  = (const float*)d_in[9];
  const float* fc1w = (const float*)d_in[10];
  const float* fc1b = (const float*)d_in[11];
  const float* fc2w = (const float*)d_in[12];
  const float* fc2b = (const float*)d_in[13];
  const float* wih1 = (const float*)d_in[14];
  const float* whh1 = (const float*)d_in[15];
  const float* bih1 = (const float*)d_in[16];
  const float* bhh1 = (const float*)d_in[17];
  const float* wih2 = (const float*)d_in[18];
  const float* whh2 = (const float*)d_in[19];
  const float* bih2 = (const float*)d_in[20];
  const float* bhh2 = (const float*)d_in[21];
  const float* outw = (const float*)d_in[22];
  const float* outb = (const float*)d_in[23];
  float* out = (float*)d_out;

  // ---- ws carve ----
  uint32_t* sent1 = (uint32_t*)d_ws;          // 64*128*16 = 131,072 u32
  uint32_t* sent2 = sent1 + 131072;           // 131,072
  u16* h1d      = (u16*)(sent2 + 131072);     // 1,048,576 u16
  u16* h2a      = h1d + 1048576;              // 1,048,576
  float* pooled = (float*)(h2a + 1048576);    // 24576
  float* ench   = pooled + 24576;             // 16384
  float* enco   = ench + 16384;               // 16384
  float* bs1    = enco + 16384;               // 2048
  float* bs2    = bs1 + 2048;                 // 2048
  float* pre    = bs2 + 2048;                 // 4,128,768
  u16* outw_bf  = (u16*)(pre + 4128768);      // 16,384,000
  u16* wih1_bf  = outw_bf + 16384000;         // 1,572,864
  u16* wih2_bf  = wih1_bf + 1572864;          // 1,048,576
  u16* whh1_bf  = wih2_bf + 1048576;          // 1,048,576
  u16* whh2_bf  = whh1_bf + 1048576;          // 1,048,576
  u16* wtj3     = whh2_bf + 1048576;          // 196,608
  u16* wtj4     = wtj3 + 196608;              // 262,144
  u16* wtj5     = wtj4 + 262144;              // 327,680
  u16* X1       = wtj5 + 327680;              // 1,572,864

  init_all<<<512, 256, 0, stream>>>(pooled, sent1, sent2, h1d, h2a,
                                    bih1, bhh1, bih2, bhh2, bs1, bs2, out);
  cvt_all<<<2048, 256, 0, stream>>>(outw, outw_bf, wih1, wih1_bf, wih2, wih2_bf,
                                    whh1, whh1_bf, whh2, whh2_bf);
  wtj_all<<<512, 256, 0, stream>>>(cw3, wtj3, cw4, wtj4, cw5, wtj5);

  conv_mfma<<<dim3(128, 2, 3), 256, 0, stream>>>(wtj3, wtj4, wtj5, cb3, cb4, cb5,
                                                 pooled, src, eemb);
  gemm_small<<<64, 256, 0, stream>>>(pooled, fc1w, fc1b, ench, 768, 512, 1);
  gemm_small<<<64, 256, 0, stream>>>(ench, fc2w, fc2b, enco, 512, 512, 0);

  build_x1<<<2048, 256, 0, stream>>>(trg, demb, enco, X1);
  gemm_mfma<<<dim3(16, 16), 256, 0, stream>>>(X1, wih1_bf, bs1, pre, 2016, 2048, 768);
  lstm_fused<<<224, 256, 0, stream>>>(pre, whh1_bf, wih2_bf, whh2_bf, bs2,
                                      sent1, sent2, h1d, h2a, outw_bf, outb, out);
}

// Round 9
// 467.293 us; speedup vs baseline: 1.1919x; 1.0086x over previous
//
#include <hip/hip_runtime.h>
#include <math.h>
#include <stdint.h>

#define B_    32
#define E_    256
#define F_    256
#define H_    512
#define V_    32000
#define G4    2048

typedef unsigned short u16;
typedef unsigned long long u64;
typedef __attribute__((ext_vector_type(8))) short bf16x8;
typedef __attribute__((ext_vector_type(4))) float f32x4;

__device__ __forceinline__ float fsig(float x) {
  return __builtin_amdgcn_rcpf(1.f + __expf(-x));
}
__device__ __forceinline__ float ftanh(float x) {
  return 1.f - 2.f * __builtin_amdgcn_rcpf(1.f + __expf(2.f * x));
}

__device__ __forceinline__ u16 f2bf(float f) {
  uint32_t u = __float_as_uint(f);
  uint32_t r = (u + 0x7FFFu + ((u >> 16) & 1u)) >> 16;   // RNE
  return (u16)r;
}
__device__ __forceinline__ uint32_t pack2(float a, float b) {
  return (uint32_t)f2bf(a) | ((uint32_t)f2bf(b) << 16);
}

#define GLOAD16(gp, lp) __builtin_amdgcn_global_load_lds( \
    (const __attribute__((address_space(1))) uint32_t*)(const void*)(gp), \
    (__attribute__((address_space(3))) uint32_t*)(void*)(lp), 16, 0, 0)

#define ALOAD(P) __hip_atomic_load((P), __ATOMIC_RELAXED, __HIP_MEMORY_SCOPE_AGENT)
#define ASTORE(P, V) __hip_atomic_store((P), (V), __ATOMIC_RELAXED, __HIP_MEMORY_SCOPE_AGENT)

// ---------------- fused init -------------------------------------------------------
__global__ void init_all(float* pooled, uint32_t* sent1, uint32_t* sent2,
                         uint32_t* cnt1, u16* h1d, u16* h2a,
                         const float* bi1, const float* bh1,
                         const float* bi2, const float* bh2,
                         float* bs1, float* bs2, float* out) {
  int i = blockIdx.x * blockDim.x + threadIdx.x, st = gridDim.x * blockDim.x;
  for (int k = i; k < 24576; k += st) pooled[k] = 0.f;
  for (int k = i; k < 131072; k += st) {
    uint32_t v = (k < 2048 && (k & 15) == 0) ? 1u : 0u;   // t=0 ready
    sent1[k] = v; sent2[k] = v;
  }
  for (int k = i; k < 256; k += st) cnt1[k] = 0u;
  uint4 z = {0u, 0u, 0u, 0u};
  for (int k = i; k < 2048; k += st) { ((uint4*)h1d)[k] = z; ((uint4*)h2a)[k] = z; }
  for (int k = i; k < G4; k += st) { bs1[k] = bi1[k] + bh1[k]; bs2[k] = bi2[k] + bh2[k]; }
  for (int k = i; k < B_ * V_; k += st) {
    int b = k / V_, v = k - b * V_;
    __builtin_nontemporal_store(0.f, &out[(size_t)b * 64 * V_ + v]);
  }
}

// ---------------- fused bf16 conversion of 5 weight tensors ------------------------
__global__ void cvt_all(const float* s0, u16* d0, const float* s1, u16* d1,
                        const float* s2, u16* d2, const float* s3, u16* d3,
                        const float* s4, u16* d4) {
  int i = blockIdx.x * blockDim.x + threadIdx.x, st = gridDim.x * blockDim.x;
  for (; i < 2637824; i += st) {
    int j = i; const float* s; u16* d;
    if (j < 2048000) { s = s0; d = d0; }
    else if ((j -= 2048000) < 196608) { s = s1; d = d1; }
    else if ((j -= 196608) < 131072) { s = s2; d = d2; }
    else if ((j -= 131072) < 131072) { s = s3; d = d3; }
    else { j -= 131072; s = s4; d = d4; }
    const float4* sp = (const float4*)s + 2 * (size_t)j;
    float4 a = sp[0], b = sp[1];
    uint4 u;
    u.x = pack2(a.x, a.y); u.y = pack2(a.z, a.w);
    u.z = pack2(b.x, b.y); u.w = pack2(b.z, b.w);
    *((uint4*)d + j) = u;
  }
}

// conv weights (F,E,kw) -> bf16 [f][j*256+e], all 3 in one kernel
__global__ void wtj_all(const float* w3, u16* t3, const float* w4, u16* t4,
                        const float* w5, u16* t5) {
  int i = blockIdx.x * blockDim.x + threadIdx.x, st = gridDim.x * blockDim.x;
  for (; i < 786432; i += st) {
    int j = i; const float* w; u16* wt; int kw;
    if (j < 196608) { w = w3; wt = t3; kw = 3; }
    else if ((j -= 196608) < 262144) { w = w4; wt = t4; kw = 4; }
    else { j -= 262144; w = w5; wt = t5; kw = 5; }
    int f = j / (kw * 256);
    int r = j - f * (kw * 256);
    int jj = r >> 8, e = r & 255;
    wt[j] = f2bf(w[(f * 256 + e) * kw + jj]);
  }
}

// ---------------- small fp32 GEMM (fc1/fc2) ----------------
__global__ void gemm_small(const float* __restrict__ A, const float* __restrict__ W,
                           const float* __restrict__ bias, float* __restrict__ C,
                           int K, int N, int relu) {
  int nl = threadIdx.x & 7, b = threadIdx.x >> 3;
  int n = blockIdx.x * 8 + nl;
  const float* a = A + b * K;
  const float* w = W + (size_t)n * K;
  float acc = 0.f;
  for (int k = 0; k < K; k += 4) {
    float4 av = *reinterpret_cast<const float4*>(&a[k]);
    float4 wv = *reinterpret_cast<const float4*>(&w[k]);
    acc = fmaf(av.x, wv.x, acc); acc = fmaf(av.y, wv.y, acc);
    acc = fmaf(av.z, wv.z, acc); acc = fmaf(av.w, wv.w, acc);
  }
  acc += bias[n];
  if (relu) acc = fmaxf(acc, 0.f);
  C[b * N + n] = acc;
}

// ---------------- conv via implicit im2col + fused relu/maxpool --------------------
__global__ __launch_bounds__(256)
void conv_mfma(const u16* __restrict__ wt3, const u16* __restrict__ wt4,
               const u16* __restrict__ wt5,
               const float* __restrict__ cb3, const float* __restrict__ cb4,
               const float* __restrict__ cb5,
               float* __restrict__ pooled,
               const int* __restrict__ srcTok, const float* __restrict__ emb) {
  const int z = blockIdx.z;
  const u16* Bw = (z == 0) ? wt3 : (z == 1) ? wt4 : wt5;
  const float* bias = (z == 0) ? cb3 : (z == 1) ? cb4 : cb5;
  const int K = 768 + 256 * z, kw = 3 + z, poolOff = 256 * z;

  __shared__ char smem[32768];
  const int tid = threadIdx.x;
  const int wid = tid >> 6, lane = tid & 63;
  const int hi = lane >> 4, lo = lane & 15;
  const int wr = wid >> 1, wc = wid & 1;
  const int m0 = blockIdx.x * 128, n0 = blockIdx.y * 128;
  const int NT = K >> 5;
  const int srow = lane >> 2, sc = lane & 3;

  f32x4 acc[4][4];
#pragma unroll
  for (int i = 0; i < 4; ++i)
#pragma unroll
    for (int j = 0; j < 4; ++j) acc[i][j] = (f32x4){0.f, 0.f, 0.f, 0.f};

  for (int t = -1; t < NT; ++t) {
    int ts = t + 1;
    if (ts < NT) {
      char* base = smem + (ts & 1) * 16384;
      int k0 = ts << 5;
      {  // A: gather from embeddings (im2col in LDS)
        int j = k0 >> 8, e0 = k0 & 255;
        int row = tid >> 1;
        int m = m0 + row;
        int s = m & 511, b = m >> 9;
        int sj = s + j;
        int tok = (sj < 512) ? srcTok[b * 512 + sj] : -1;
#pragma unroll
        for (int q = 0; q < 2; ++q) {
          int cg = (tid & 1) * 2 + q;
          uint4 u;
          if (tok >= 0) {
            const float* ep = emb + (size_t)tok * 256 + e0 + cg * 8;
            float4 f0 = *(const float4*)(ep);
            float4 f1 = *(const float4*)(ep + 4);
            u.x = pack2(f0.x, f0.y); u.y = pack2(f0.z, f0.w);
            u.z = pack2(f1.x, f1.y); u.w = pack2(f1.z, f1.w);
          } else u = (uint4){0, 0, 0, 0};
          int c = cg ^ (row & 3);
          *(uint4*)(base + row * 64 + c * 16) = u;
        }
      }
#pragma unroll
      for (int q = 0; q < 2; ++q) {
        int row = (wid + q * 4) * 16 + srow;
        int gc = sc ^ (row & 3);
        const char* gp = (const char*)Bw + (((size_t)(n0 + row) * K + k0) << 1) + gc * 16;
        GLOAD16(gp, base + 8192 + (wid + q * 4) * 1024);
      }
    }
    if (t >= 0) {
      char* base = smem + (t & 1) * 16384;
      bf16x8 af[4], bfr[4];
#pragma unroll
      for (int mi = 0; mi < 4; ++mi) {
        int row = wr * 64 + mi * 16 + lo;
        af[mi] = *(const bf16x8*)(base + row * 64 + ((hi ^ (row & 3)) << 4));
      }
#pragma unroll
      for (int ni = 0; ni < 4; ++ni) {
        int row = wc * 64 + ni * 16 + lo;
        bfr[ni] = *(const bf16x8*)(base + 8192 + row * 64 + ((hi ^ (row & 3)) << 4));
      }
#pragma unroll
      for (int mi = 0; mi < 4; ++mi)
#pragma unroll
        for (int ni = 0; ni < 4; ++ni)
          acc[mi][ni] = __builtin_amdgcn_mfma_f32_16x16x32_bf16(af[mi], bfr[ni], acc[mi][ni], 0, 0, 0);
    }
    __syncthreads();
  }

  int b = m0 >> 9;
  int slim = 512 - kw;
#pragma unroll
  for (int ni = 0; ni < 4; ++ni) {
    int col = n0 + wc * 64 + ni * 16 + lo;
    float bv = bias[col];
    float mx = 0.f;
#pragma unroll
    for (int mi = 0; mi < 4; ++mi)
#pragma unroll
      for (int r = 0; r < 4; ++r) {
        int m = m0 + wr * 64 + mi * 16 + hi * 4 + r;
        int s = m & 511;
        float v = acc[mi][ni][r] + bv;
        if (s <= slim && v > mx) mx = v;
      }
    atomicMax((int*)&pooled[b * 768 + poolOff + col], __float_as_int(mx));
  }
}

// ---------------- mega persistent kernel ------------------------------------------
// Blocks 0..31: L1 recurrence (polls cnt1[rt] for pre readiness + sent1 flags).
// Blocks 32..63: L2 recurrence.  Blocks 64..223: phase0 = pre1 GEMM tiles (inline
// X1 gather from demb/enco, per-rt counters), phase1 = out-projection tiles
// consuming sent2 flags in t-order, with non-temporal out stores.
__global__ __launch_bounds__(256, 1)
void lstm_fused(float* __restrict__ pre,
                const u16* __restrict__ whh1,
                const u16* __restrict__ wih2, const u16* __restrict__ whh2,
                const float* __restrict__ bs2,
                uint32_t* __restrict__ sent1, uint32_t* __restrict__ sent2,
                uint32_t* __restrict__ cnt1,
                u16* __restrict__ h1d, u16* __restrict__ h2a,
                const u16* __restrict__ outw_bf, const float* __restrict__ outb,
                float* __restrict__ out,
                const int* __restrict__ trg, const float* __restrict__ demb,
                const float* __restrict__ enco,
                const u16* __restrict__ wih1_bf, const float* __restrict__ bs1) {
  __shared__ char smem[74752];
  const int tid = threadIdx.x;
  const int wid = tid >> 6, lane = tid & 63, hi = lane >> 4, lo = lane & 15;
  const int hrow = tid >> 3, k8 = tid & 7;
  const int pb = hrow, pj0 = k8 * 2;

#define WAVE_DRAIN() asm volatile("s_waitcnt vmcnt(0)" ::: "memory")
#define POLL1(P) while (ALOAD(P) == 0u) __builtin_amdgcn_s_sleep(1);
#define POLL2(P, Q) for (;;) { uint32_t x_ = ALOAD(P), y_ = ALOAD(Q); \
                               if (x_ & y_) break; __builtin_amdgcn_s_sleep(1); }
#define POLL2S(P, Q) for (;;) { uint32_t x_ = ALOAD(P), y_ = ALOAD(Q); \
                                if (x_ & y_) break; __builtin_amdgcn_s_sleep(16); }

  if (blockIdx.x < 32) {
    // -------- layer 1 --------
    const int bi = blockIdx.x;
    u16* hlds = (u16*)smem;                   // [32][520] u16
    float* glds = (float*)(smem + 33280);     // [4][32][17] f32

    bf16x8 wreg[16];
    const u16* wp = whh1 + (((size_t)(wid * 512 + bi * 16 + lo)) << 9) + hi * 8;
#pragma unroll
    for (int ks = 0; ks < 16; ++ks) wreg[ks] = *(const bf16x8*)(wp + ks * 32);

    float creg0 = 0.f, creg1 = 0.f;

    for (int t = 0; t < 63; ++t) {
      if ((t & 3) == 0) {                    // pre tile-row rt = t>>2 readiness
        if (tid == 0)
          while (ALOAD(cnt1 + (t >> 2) * 16) < 16u) __builtin_amdgcn_s_sleep(8);
        __syncthreads();
      }
      const float* pr = pre + (((size_t)(t * 32 + pb)) << 11) + bi * 16 + pj0;
      float pi0 = pr[0], pf0 = pr[512], pg0 = pr[1024], po0 = pr[1536];
      float pi1 = pr[1], pf1 = pr[513], pg1 = pr[1025], po1 = pr[1537];

      const u64* hp = (const u64*)(h1d + ((size_t)t * 32 + hrow) * 512);
      f32x4 acc0 = (f32x4){0.f,0.f,0.f,0.f}, acc1 = (f32x4){0.f,0.f,0.f,0.f};

      POLL1(sent1 + (size_t)t * 2048 + lane * 16)
      {
        u64 v[8];
#pragma unroll
        for (int g = 0; g < 4; ++g) {
          int c = k8 + 8 * g;
          v[2*g]   = ALOAD(hp + 2 * c);
          v[2*g+1] = ALOAD(hp + 2 * c + 1);
        }
#pragma unroll
        for (int g = 0; g < 4; ++g) {
          int c = k8 + 8 * g;
          u64 w2[2] = { v[2*g], v[2*g+1] };
          *(uint4*)(hlds + hrow * 520 + c * 8) = *(const uint4*)w2;
        }
      }
      __syncthreads();
#pragma unroll
      for (int ks = 0; ks < 8; ++ks) {
        int cg = (ks * 4 + hi) * 8;
        bf16x8 a0 = *(const bf16x8*)(hlds + lo * 520 + cg);
        bf16x8 a1 = *(const bf16x8*)(hlds + (16 + lo) * 520 + cg);
        acc0 = __builtin_amdgcn_mfma_f32_16x16x32_bf16(a0, wreg[ks], acc0, 0, 0, 0);
        acc1 = __builtin_amdgcn_mfma_f32_16x16x32_bf16(a1, wreg[ks], acc1, 0, 0, 0);
      }
      POLL1(sent1 + (size_t)t * 2048 + (64 + lane) * 16)
      {
        u64 v[8];
#pragma unroll
        for (int g = 0; g < 4; ++g) {
          int c = 32 + k8 + 8 * g;
          v[2*g]   = ALOAD(hp + 2 * c);
          v[2*g+1] = ALOAD(hp + 2 * c + 1);
        }
#pragma unroll
        for (int g = 0; g < 4; ++g) {
          int c = 32 + k8 + 8 * g;
          u64 w2[2] = { v[2*g], v[2*g+1] };
          *(uint4*)(hlds + hrow * 520 + c * 8) = *(const uint4*)w2;
        }
      }
      __syncthreads();
#pragma unroll
      for (int ks = 8; ks < 16; ++ks) {
        int cg = (ks * 4 + hi) * 8;
        bf16x8 a0 = *(const bf16x8*)(hlds + lo * 520 + cg);
        bf16x8 a1 = *(const bf16x8*)(hlds + (16 + lo) * 520 + cg);
        acc0 = __builtin_amdgcn_mfma_f32_16x16x32_bf16(a0, wreg[ks], acc0, 0, 0, 0);
        acc1 = __builtin_amdgcn_mfma_f32_16x16x32_bf16(a1, wreg[ks], acc1, 0, 0, 0);
      }
#pragma unroll
      for (int r = 0; r < 4; ++r) {
        glds[wid * 544 + (hi * 4 + r) * 17 + lo] = acc0[r];
        glds[wid * 544 + (16 + hi * 4 + r) * 17 + lo] = acc1[r];
      }
      __syncthreads();

      float iv0 = glds[0*544 + pb*17 + pj0]   + pi0, fv0 = glds[1*544 + pb*17 + pj0]   + pf0;
      float gv0 = glds[2*544 + pb*17 + pj0]   + pg0, ov0 = glds[3*544 + pb*17 + pj0]   + po0;
      float iv1 = glds[0*544 + pb*17 + pj0+1] + pi1, fv1 = glds[1*544 + pb*17 + pj0+1] + pf1;
      float gv1 = glds[2*544 + pb*17 + pj0+1] + pg1, ov1 = glds[3*544 + pb*17 + pj0+1] + po1;
      float cn0 = fsig(fv0) * creg0 + fsig(iv0) * ftanh(gv0);
      float hn0 = fsig(ov0) * ftanh(cn0);
      float cn1 = fsig(fv1) * creg1 + fsig(iv1) * ftanh(gv1);
      float hn1 = fsig(ov1) * ftanh(cn1);
      creg0 = cn0; creg1 = cn1;
      ASTORE((uint32_t*)(h1d + ((size_t)(t + 1) * 32 + pb) * 512 + bi * 16 + pj0),
             pack2(hn0, hn1));
      WAVE_DRAIN();
      if (lane == 0)
        ASTORE(sent1 + (size_t)(t + 1) * 2048 + (bi * 4 + wid) * 16, 1u);
    }
  } else if (blockIdx.x < 64) {
    // -------- layer 2 --------
    const int bi2 = blockIdx.x - 32;
    u16* alds = (u16*)smem;                   // [32][1032] u16
    float* glds = (float*)(smem + 66048);     // [4][32][17] f32

    bf16x8 wreg[32];
    {
      const u16* wa = wih2 + (((size_t)(wid * 512 + bi2 * 16 + lo)) << 9) + hi * 8;
      const u16* wb = whh2 + (((size_t)(wid * 512 + bi2 * 16 + lo)) << 9) + hi * 8;
#pragma unroll
      for (int ks = 0; ks < 16; ++ks) {
        wreg[ks]      = *(const bf16x8*)(wa + ks * 32);
        wreg[16 + ks] = *(const bf16x8*)(wb + ks * 32);
      }
    }
    float bsv0 = bs2[0 * 512 + bi2 * 16 + pj0], bsv0b = bs2[0 * 512 + bi2 * 16 + pj0 + 1];
    float bsv1 = bs2[1 * 512 + bi2 * 16 + pj0], bsv1b = bs2[1 * 512 + bi2 * 16 + pj0 + 1];
    float bsv2 = bs2[2 * 512 + bi2 * 16 + pj0], bsv2b = bs2[2 * 512 + bi2 * 16 + pj0 + 1];
    float bsv3 = bs2[3 * 512 + bi2 * 16 + pj0], bsv3b = bs2[3 * 512 + bi2 * 16 + pj0 + 1];

    float creg0 = 0.f, creg1 = 0.f;

    for (int t = 0; t < 63; ++t) {
      f32x4 acc0 = (f32x4){0.f,0.f,0.f,0.f}, acc1 = (f32x4){0.f,0.f,0.f,0.f};

      POLL2(sent1 + (size_t)(t + 1) * 2048 + lane * 16,
            sent1 + (size_t)(t + 1) * 2048 + (64 + lane) * 16)
      {
        const u64* hp1 = (const u64*)(h1d + ((size_t)(t + 1) * 32 + hrow) * 512);
        u64 v[16];
#pragma unroll
        for (int g = 0; g < 8; ++g) {
          int c = k8 + 8 * g;
          v[2*g]   = ALOAD(hp1 + 2 * c);
          v[2*g+1] = ALOAD(hp1 + 2 * c + 1);
        }
#pragma unroll
        for (int g = 0; g < 8; ++g) {
          int c = k8 + 8 * g;
          u64 w2[2] = { v[2*g], v[2*g+1] };
          *(uint4*)(alds + hrow * 1032 + c * 8) = *(const uint4*)w2;
        }
      }
      __syncthreads();
#pragma unroll
      for (int ks = 0; ks < 16; ++ks) {
        int cg = (ks * 4 + hi) * 8;
        bf16x8 a0 = *(const bf16x8*)(alds + lo * 1032 + cg);
        bf16x8 a1 = *(const bf16x8*)(alds + (16 + lo) * 1032 + cg);
        acc0 = __builtin_amdgcn_mfma_f32_16x16x32_bf16(a0, wreg[ks], acc0, 0, 0, 0);
        acc1 = __builtin_amdgcn_mfma_f32_16x16x32_bf16(a1, wreg[ks], acc1, 0, 0, 0);
      }
      POLL2(sent2 + (size_t)t * 2048 + lane * 16,
            sent2 + (size_t)t * 2048 + (64 + lane) * 16)
      {
        const u64* hp2 = (const u64*)(h2a + ((size_t)t * 32 + hrow) * 512);
        u64 v[16];
#pragma unroll
        for (int g = 0; g < 8; ++g) {
          int c = k8 + 8 * g;
          v[2*g]   = ALOAD(hp2 + 2 * c);
          v[2*g+1] = ALOAD(hp2 + 2 * c + 1);
        }
#pragma unroll
        for (int g = 0; g < 8; ++g) {
          int c = 64 + k8 + 8 * g;
          u64 w2[2] = { v[2*g], v[2*g+1] };
          *(uint4*)(alds + hrow * 1032 + c * 8) = *(const uint4*)w2;
        }
      }
      __syncthreads();
#pragma unroll
      for (int ks = 0; ks < 16; ++ks) {
        int cg = (64 + ks * 4 + hi) * 8;
        bf16x8 a0 = *(const bf16x8*)(alds + lo * 1032 + cg);
        bf16x8 a1 = *(const bf16x8*)(alds + (16 + lo) * 1032 + cg);
        acc0 = __builtin_amdgcn_mfma_f32_16x16x32_bf16(a0, wreg[16 + ks], acc0, 0, 0, 0);
        acc1 = __builtin_amdgcn_mfma_f32_16x16x32_bf16(a1, wreg[16 + ks], acc1, 0, 0, 0);
      }
#pragma unroll
      for (int r = 0; r < 4; ++r) {
        glds[wid * 544 + (hi * 4 + r) * 17 + lo] = acc0[r];
        glds[wid * 544 + (16 + hi * 4 + r) * 17 + lo] = acc1[r];
      }
      __syncthreads();

      float gi0 = glds[0*544 + pb*17 + pj0]   + bsv0,  gf0 = glds[1*544 + pb*17 + pj0]   + bsv1;
      float gg0 = glds[2*544 + pb*17 + pj0]   + bsv2,  go0 = glds[3*544 + pb*17 + pj0]   + bsv3;
      float gi1 = glds[0*544 + pb*17 + pj0+1] + bsv0b, gf1 = glds[1*544 + pb*17 + pj0+1] + bsv1b;
      float gg1 = glds[2*544 + pb*17 + pj0+1] + bsv2b, go1 = glds[3*544 + pb*17 + pj0+1] + bsv3b;
      float cn0 = fsig(gf0) * creg0 + fsig(gi0) * ftanh(gg0);
      float hn0 = fsig(go0) * ftanh(cn0);
      float cn1 = fsig(gf1) * creg1 + fsig(gi1) * ftanh(gg1);
      float hn1 = fsig(go1) * ftanh(cn1);
      creg0 = cn0; creg1 = cn1;
      ASTORE((uint32_t*)(h2a + ((size_t)(t + 1) * 32 + pb) * 512 + bi2 * 16 + pj0),
             pack2(hn0, hn1));
      WAVE_DRAIN();
      if (lane == 0)
        ASTORE(sent2 + (size_t)(t + 1) * 2048 + (bi2 * 4 + wid) * 16, 1u);
    }
  } else {
    // -------- worker group: phase 0 = pre1 GEMM tiles, phase 1 = out tiles --------
    const int bid2 = blockIdx.x - 64;             // 0..159
    const int wr = wid >> 1, wc = wid & 1;
    const int srow = lane >> 2, sc = lane & 3;

    // ---- phase 0: pre1 = [demb|enco] @ wih1^T + bs1, tiles rt(16) x ct(16) ----
    for (int w = bid2; w < 256; w += 160) {
      int rt = w >> 4, ct = w & 15;
      const int m0 = rt * 128, n0 = ct * 128;
      f32x4 acc[4][4];
#pragma unroll
      for (int i = 0; i < 4; ++i)
#pragma unroll
        for (int j = 0; j < 4; ++j) acc[i][j] = (f32x4){0.f, 0.f, 0.f, 0.f};

      for (int t = -1; t < 24; ++t) {
        int ts = t + 1;
        if (ts < 24) {
          char* base = smem + (ts & 1) * 16384;
          int k0 = ts << 5;
          {  // A: gather X1 row = [demb[tok] | enco[b]] (f32 -> bf16 inline)
            int row = tid >> 1;
            int m = m0 + row;
            int tt = m >> 5, b = m & 31;
            int ok = (m < 2016);
            int tok = ok ? trg[b * 64 + tt] : 0;
#pragma unroll
            for (int q = 0; q < 2; ++q) {
              int cg = (tid & 1) * 2 + q;
              int k = k0 + cg * 8;
              uint4 u;
              if (ok) {
                const float* ep = (k < 256) ? (demb + (size_t)tok * 256 + k)
                                            : (enco + (size_t)b * 512 + (k - 256));
                float4 f0 = *(const float4*)(ep);
                float4 f1 = *(const float4*)(ep + 4);
                u.x = pack2(f0.x, f0.y); u.y = pack2(f0.z, f0.w);
                u.z = pack2(f1.x, f1.y); u.w = pack2(f1.z, f1.w);
              } else u = (uint4){0, 0, 0, 0};
              int c = cg ^ (row & 3);
              *(uint4*)(base + row * 64 + c * 16) = u;
            }
          }
#pragma unroll
          for (int q = 0; q < 2; ++q) {      // B: wih1_bf rows (N=2048, K=768)
            int row = (wid + q * 4) * 16 + srow;
            int gc = sc ^ (row & 3);
            const char* gp = (const char*)wih1_bf + (((size_t)(n0 + row) * 768 + k0) << 1) + gc * 16;
            GLOAD16(gp, base + 8192 + (wid + q * 4) * 1024);
          }
        }
        if (t >= 0) {
          char* base = smem + (t & 1) * 16384;
          bf16x8 af[4], bfr[4];
#pragma unroll
          for (int mi = 0; mi < 4; ++mi) {
            int row = wr * 64 + mi * 16 + lo;
            af[mi] = *(const bf16x8*)(base + row * 64 + ((hi ^ (row & 3)) << 4));
          }
#pragma unroll
          for (int ni = 0; ni < 4; ++ni) {
            int row = wc * 64 + ni * 16 + lo;
            bfr[ni] = *(const bf16x8*)(base + 8192 + row * 64 + ((hi ^ (row & 3)) << 4));
          }
#pragma unroll
          for (int mi = 0; mi < 4; ++mi)
#pragma unroll
            for (int ni = 0; ni < 4; ++ni)
              acc[mi][ni] = __builtin_amdgcn_mfma_f32_16x16x32_bf16(af[mi], bfr[ni], acc[mi][ni], 0, 0, 0);
        }
        __syncthreads();
      }
      // epilogue: agent-scope stores (cross-XCD visible), then count the tile
#pragma unroll
      for (int mi = 0; mi < 4; ++mi)
#pragma unroll
        for (int r = 0; r < 4; ++r) {
          int m = m0 + wr * 64 + mi * 16 + hi * 4 + r;
          if (m >= 2016) continue;
#pragma unroll
          for (int ni = 0; ni < 4; ++ni) {
            int col = n0 + wc * 64 + ni * 16 + lo;
            ASTORE((uint32_t*)(pre + (size_t)m * 2048 + col),
                   __float_as_uint(acc[mi][ni][r] + bs1[col]));
          }
        }
      WAVE_DRAIN();
      __syncthreads();
      if (tid == 0)
        __hip_atomic_fetch_add(cnt1 + rt * 16, 1u, __ATOMIC_RELAXED, __HIP_MEMORY_SCOPE_AGENT);
      __syncthreads();
    }

    // ---- phase 1: out-projection tiles over (rt 0..15, ct 0..249) ----
    const u16* A = h2a + 16384;                   // row r -> slot (r>>5)+1

    for (int w = bid2; w < 16 * 250; w += 160) {
      int rt = w / 250, ct = w - rt * 250;
      int tf = rt * 4 + 4; if (tf > 63) tf = 63;
      if (wid == 0)
        POLL2S(sent2 + (size_t)tf * 2048 + lane * 16,
               sent2 + (size_t)tf * 2048 + (64 + lane) * 16)
      __syncthreads();

      const int m0 = rt * 128, n0 = ct * 128;
      f32x4 acc[4][4];
#pragma unroll
      for (int i = 0; i < 4; ++i)
#pragma unroll
        for (int j = 0; j < 4; ++j) acc[i][j] = (f32x4){0.f, 0.f, 0.f, 0.f};

      for (int t = -1; t < 16; ++t) {
        int ts = t + 1;
        if (ts < 16) {
          char* base = smem + (ts & 1) * 16384;
          int k0 = ts << 5;
#pragma unroll
          for (int q = 0; q < 2; ++q) {
            int row = (wid + q * 4) * 16 + srow;
            int gc = sc ^ (row & 3);
            const char* gp = (const char*)A + (((size_t)(m0 + row) * 512 + k0) << 1) + gc * 16;
            GLOAD16(gp, base + (wid + q * 4) * 1024);
          }
#pragma unroll
          for (int q = 0; q < 2; ++q) {
            int row = (wid + q * 4) * 16 + srow;
            int gc = sc ^ (row & 3);
            const char* gp = (const char*)outw_bf + (((size_t)(n0 + row) * 512 + k0) << 1) + gc * 16;
            GLOAD16(gp, base + 8192 + (wid + q * 4) * 1024);
          }
        }
        if (t >= 0) {
          char* base = smem + (t & 1) * 16384;
          bf16x8 af[4], bfr[4];
#pragma unroll
          for (int mi = 0; mi < 4; ++mi) {
            int row = wr * 64 + mi * 16 + lo;
            af[mi] = *(const bf16x8*)(base + row * 64 + ((hi ^ (row & 3)) << 4));
          }
#pragma unroll
          for (int ni = 0; ni < 4; ++ni) {
            int row = wc * 64 + ni * 16 + lo;
            bfr[ni] = *(const bf16x8*)(base + 8192 + row * 64 + ((hi ^ (row & 3)) << 4));
          }
#pragma unroll
          for (int mi = 0; mi < 4; ++mi)
#pragma unroll
            for (int ni = 0; ni < 4; ++ni)
              acc[mi][ni] = __builtin_amdgcn_mfma_f32_16x16x32_bf16(af[mi], bfr[ni], acc[mi][ni], 0, 0, 0);
        }
        __syncthreads();
      }

#pragma unroll
      for (int mi = 0; mi < 4; ++mi)
#pragma unroll
        for (int r = 0; r < 4; ++r) {
          int m = m0 + wr * 64 + mi * 16 + hi * 4 + r;
          if (m >= 2016) continue;
          int t2 = m >> 5, b = m & 31;
          size_t rowbase = ((size_t)b * 64 + t2 + 1) * (size_t)V_;
#pragma unroll
          for (int ni = 0; ni < 4; ++ni) {
            int col = n0 + wc * 64 + ni * 16 + lo;
            __builtin_nontemporal_store(acc[mi][ni][r] + outb[col], &out[rowbase + col]);
          }
        }
    }
  }
#undef POLL1
#undef POLL2
#undef POLL2S
#undef WAVE_DRAIN
}

// ---------------- host ----------------
extern "C" void kernel_launch(void* const* d_in, const int* in_sizes, int n_in,
                              void* d_out, int out_size, void* d_ws, size_t ws_size,
                              hipStream_t stream) {
  const int*   src  = (const int*)  d_in[0];
  const int*   trg  = (const int*)  d_in[1];
  const float* eemb = (const float*)d_in[2];
  const float* demb = (const float*)d_in[3];
  const float* cw3  = (const float*)d_in[4];
  const float* cb3  = (const float*)d_in[5];
  const float* cw4  = (const float*)d_in[6];
  const float* cb4  = (const float*)d_in[7];
  const float* cw5  = (const float*)d_in[8];
  const float* cb5  = (const float*)d_in[9];
  const float* fc1w = (const float*)d_in[10];
  const float* fc1b = (const float*)d_in[11];
  const float* fc2w = (const float*)d_in[12];
  const float* fc2b = (const float*)d_in[13];
  const float* wih1 = (const float*)d_in[14];
  const float* whh1 = (const float*)d_in[15];
  const float* bih1 = (const float*)d_in[16];
  const float* bhh1 = (const float*)d_in[17];
  const float* wih2 = (const float*)d_in[18];
  const float* whh2 = (const float*)d_in[19];
  const float* bih2 = (const float*)d_in[20];
  const float* bhh2 = (const float*)d_in[21];
  const float* outw = (const float*)d_in[22];
  const float* outb = (const float*)d_in[23];
  float* out = (float*)d_out;

  // ---- ws carve ----
  uint32_t* sent1 = (uint32_t*)d_ws;          // 131,072 u32
  uint32_t* sent2 = sent1 + 131072;           // 131,072
  uint32_t* cnt1  = sent2 + 131072;           // 256
  u16* h1d      = (u16*)(cnt1 + 256);         // 1,048,576 u16
  u16* h2a      = h1d + 1048576;              // 1,048,576
  float* pooled = (float*)(h2a + 1048576);    // 24576
  float* ench   = pooled + 24576;             // 16384
  float* enco   = ench + 16384;               // 16384
  float* bs1    = enco + 16384;               // 2048
  float* bs2    = bs1 + 2048;                 // 2048
  float* pre    = bs2 + 2048;                 // 4,128,768
  u16* outw_bf  = (u16*)(pre + 4128768);      // 16,384,000
  u16* wih1_bf  = outw_bf + 16384000;         // 1,572,864
  u16* wih2_bf  = wih1_bf + 1572864;          // 1,048,576
  u16* whh1_bf  = wih2_bf + 1048576;          // 1,048,576
  u16* whh2_bf  = whh1_bf + 1048576;          // 1,048,576
  u16* wtj3     = whh2_bf + 1048576;          // 196,608
  u16* wtj4     = wtj3 + 196608;              // 262,144
  u16* wtj5     = wtj4 + 262144;              // 327,680

  init_all<<<512, 256, 0, stream>>>(pooled, sent1, sent2, cnt1, h1d, h2a,
                                    bih1, bhh1, bih2, bhh2, bs1, bs2, out);
  cvt_all<<<2048, 256, 0, stream>>>(outw, outw_bf, wih1, wih1_bf, wih2, wih2_bf,
                                    whh1, whh1_bf, whh2, whh2_bf);
  wtj_all<<<512, 256, 0, stream>>>(cw3, wtj3, cw4, wtj4, cw5, wtj5);

  conv_mfma<<<dim3(128, 2, 3), 256, 0, stream>>>(wtj3, wtj4, wtj5, cb3, cb4, cb5,
                                                 pooled, src, eemb);
  gemm_small<<<64, 256, 0, stream>>>(pooled, fc1w, fc1b, ench, 768, 512, 1);
  gemm_small<<<64, 256, 0, stream>>>(ench, fc2w, fc2b, enco, 512, 512, 0);

  lstm_fused<<<224, 256, 0, stream>>>(pre, whh1_bf, wih2_bf, whh2_bf, bs2,
                                      sent1, sent2, cnt1, h1d, h2a,
                                      outw_bf, outb, out,
                                      trg, demb, enco, wih1_bf, bs1);
}